// Round 11
// baseline (470.787 us; speedup 1.0000x reference)
//
#include <hip/hip_runtime.h>
#include <cstdint>
#include <cstddef>

typedef unsigned short u16;
typedef _Float16 f16x8 __attribute__((ext_vector_type(8)));
typedef _Float16 h2 __attribute__((ext_vector_type(2)));
typedef float f32x4 __attribute__((ext_vector_type(4)));

__device__ __forceinline__ float h2f(u16 u) {
  return (float)__builtin_bit_cast(_Float16, u);
}
__device__ __forceinline__ u16 f2h(float f) {
  return __builtin_bit_cast(u16, (_Float16)f);
}

// async 16B global -> LDS (gfx950)
__device__ __forceinline__ void async16(u16* lds, const u16* g) {
  __builtin_amdgcn_global_load_lds(
      (const __attribute__((address_space(1))) unsigned int*)g,
      (__attribute__((address_space(3))) unsigned int*)lds, 16, 0, 0);
}

// fp32 unpack-fma (final layer, fp32 accumulation)
__device__ __forceinline__ void fma8(float* a, float d, uint4 p) {
  a[0] += d * h2f((u16)p.x); a[1] += d * h2f((u16)(p.x >> 16));
  a[2] += d * h2f((u16)p.y); a[3] += d * h2f((u16)(p.y >> 16));
  a[4] += d * h2f((u16)p.z); a[5] += d * h2f((u16)(p.z >> 16));
  a[6] += d * h2f((u16)p.w); a[7] += d * h2f((u16)(p.w >> 16));
}

// packed f16 fma: acc[j] += h2(p word j) * w
__device__ __forceinline__ void pkfma4(h2* acc, h2 w, uint4 p) {
  acc[0] += __builtin_bit_cast(h2, p.x) * w;
  acc[1] += __builtin_bit_cast(h2, p.y) * w;
  acc[2] += __builtin_bit_cast(h2, p.z) * w;
  acc[3] += __builtin_bit_cast(h2, p.w) * w;
}

// per-wave int64-vs-int32 edge dtype detection (first 1KB, L2-hot)
__device__ __forceinline__ int wave_is64(const void* ep) {
  const unsigned* p = (const unsigned*)ep;
  const int lane = threadIdx.x & 63;
  unsigned v = p[2 * lane + 1] | p[2 * (lane + 64) + 1];
  unsigned long long bal = __ballot(v != 0u);
  return (bal == 0ull) ? 1 : 0;
}

__device__ __forceinline__ int edge_at(const void* ep, int is64, long long idx) {
  if (is64) return (int)((const long long*)ep)[idx];
  return ((const int*)ep)[idx];
}

#define NCHUNK 64

// ---------------- diagnostics / fallback ----------------
__global__ void zero_f32(float* p, int n) {
  int i = blockIdx.x * 256 + threadIdx.x;
  if (i < n) p[i] = 0.f;
}

// ---------------- prep_all: cvt_pad + 3x transpose_w + csr_hist + sync-zero ----
__global__ __launch_bounds__(256) void prep_all(
    const float4* __restrict__ x, ushort4* __restrict__ xpad, int n_src4, int n_tot4,
    const float* __restrict__ W1, u16* __restrict__ wt1,
    const float* __restrict__ W2, u16* __restrict__ wt2,
    const float* __restrict__ W3, u16* __restrict__ wt3,
    const void* __restrict__ ep, int* __restrict__ cnt, int* __restrict__ sync,
    int E, int N, int DIN, int DH, int DOUT,
    int nb_cvt, int nb_w1, int nb_w2, int nb_w3) {
  int b = blockIdx.x;
  if (b < nb_cvt) {                       // fp32 -> f16 convert + pad
    int i = b * 256 + threadIdx.x;
    if (i < n_tot4) {
      ushort4 o = {0, 0, 0, 0};
      if (i < n_src4) {
        float4 v = x[i];
        o.x = f2h(v.x); o.y = f2h(v.y); o.z = f2h(v.z); o.w = f2h(v.w);
      }
      xpad[i] = o;
    }
    return;
  }
  b -= nb_cvt;
  if (b < nb_w1) {                        // wt1[n*DIN+k] = W1[k*DH+n]
    int idx = b * 256 + threadIdx.x;
    if (idx < DIN * DH) {
      int n = idx / DIN, k = idx % DIN;
      wt1[idx] = f2h(W1[k * DH + n]);
    }
    return;
  }
  b -= nb_w1;
  if (b < nb_w2) {                        // wt2[n*DH+k] = W2[k*DH+n]
    int idx = b * 256 + threadIdx.x;
    if (idx < DH * DH) {
      int n = idx / DH, k = idx % DH;
      wt2[idx] = f2h(W2[k * DH + n]);
    }
    return;
  }
  b -= nb_w2;
  if (b < nb_w3) {                        // wt3[n*DH+k] = W3[k*DOUT+n]
    int idx = b * 256 + threadIdx.x;
    if (idx < DH * DOUT) {
      int n = idx / DH, k = idx % DH;
      wt3[idx] = f2h(W3[k * DOUT + n]);
    }
    return;
  }
  b -= nb_w3;
  if (b < NCHUNK) {                       // per-chunk bucket histogram
    __shared__ int h[256];
    h[threadIdx.x] = 0;
    __syncthreads();
    int is64 = wave_is64(ep);
    const int per = (E + NCHUNK - 1) / NCHUNK;
    const int e0 = b * per, e1 = min(e0 + per, E);
    for (int e = e0 + (int)threadIdx.x; e < e1; e += 256) {
      int d = edge_at(ep, is64, (long long)E + e);
      d = min(max(d, 0), N - 1);
      atomicAdd(&h[d >> 8], 1);
    }
    __syncthreads();
    cnt[threadIdx.x * NCHUNK + b] = h[threadIdx.x];
    return;
  }
  b -= NCHUNK;
  {                                       // zero sync counters
    if (threadIdx.x < 16) sync[threadIdx.x] = 0;
  }
}

// ---------------- csr_all: base + bucket-scatter + final, one kernel ---------
// grid = max(nbuck, NCHUNK) blocks, ALL co-resident (<=256). Internal barriers
// via device-scope atomics (sync[] zeroed by prep_all).
__global__ __launch_bounds__(256) void csr_all(const void* __restrict__ ep,
                                               const int* __restrict__ cnt,
                                               int* __restrict__ bases,
                                               int* __restrict__ offs,
                                               unsigned* __restrict__ tmp,
                                               int* __restrict__ rp,
                                               float* __restrict__ dis,
                                               u16* __restrict__ col,
                                               int* __restrict__ sync,
                                               int E, int N, int nbuck) {
  __shared__ int sh[256];
  __shared__ int sh2[256];
  __shared__ int ws4[8];
  const int b = blockIdx.x, t = threadIdx.x, lane = t & 63, w = t >> 6;

  // ---- phase A: block 0 computes bases + per-(bucket,chunk) offsets ----
  if (b == 0) {
    int tot = 0;
    if (t < nbuck)
      for (int c = 0; c < NCHUNK; ++c) tot += cnt[t * NCHUNK + c];
    int inc = tot;
#pragma unroll
    for (int o = 1; o < 64; o <<= 1) {
      int u = __shfl_up(inc, o, 64);
      if (lane >= o) inc += u;
    }
    if (lane == 63) ws4[w] = inc;
    __syncthreads();
    if (t == 0) {
      int run = 0;
#pragma unroll
      for (int k = 0; k < 4; ++k) { int v = ws4[k]; ws4[k + 4] = run; run += v; }
    }
    __syncthreads();
    int base = ws4[w + 4] + inc - tot;
    if (t < nbuck) {
      bases[t] = base;
      int run = base;
      for (int c = 0; c < NCHUNK; ++c) {
        offs[t * NCHUNK + c] = run;
        run += cnt[t * NCHUNK + c];
      }
    }
    if (t == 0) bases[nbuck] = E;
    __threadfence();
    __syncthreads();
    if (t == 0)
      __hip_atomic_store(&sync[0], 1, __ATOMIC_RELEASE, __HIP_MEMORY_SCOPE_AGENT);
  } else {
    if (t == 0) {
      while (__hip_atomic_load(&sync[0], __ATOMIC_ACQUIRE, __HIP_MEMORY_SCOPE_AGENT) == 0)
        __builtin_amdgcn_s_sleep(8);
    }
    __syncthreads();
  }

  // ---- phase B: blocks < NCHUNK scatter their chunk into bucket runs ----
  if (b < NCHUNK) {
    if (t < nbuck) sh[t] = offs[t * NCHUNK + b];
    __syncthreads();
    int is64 = wave_is64(ep);
    const int per = (E + NCHUNK - 1) / NCHUNK;
    const int e0 = b * per, e1 = min(e0 + per, E);
    for (int e = e0 + t; e < e1; e += 256) {
      int s = edge_at(ep, is64, e);
      int d = edge_at(ep, is64, (long long)E + e);
      s = min(max(s, 0), N - 1);
      d = min(max(d, 0), N - 1);
      int pos = atomicAdd(&sh[d >> 8], 1);
      tmp[pos] = ((unsigned)d << 16) | (unsigned)s;
    }
    __threadfence();
    __syncthreads();
    if (t == 0)
      __hip_atomic_fetch_add(&sync[1], 1, __ATOMIC_RELEASE, __HIP_MEMORY_SCOPE_AGENT);
  }
  if (t == 0) {
    while (__hip_atomic_load(&sync[1], __ATOMIC_ACQUIRE, __HIP_MEMORY_SCOPE_AGENT) < NCHUNK)
      __builtin_amdgcn_s_sleep(8);
  }
  __syncthreads();

  // ---- phase C: per-bucket node histogram -> rp/dis + col scatter ----
  if (b >= nbuck) return;
  sh[t] = 0;
  __syncthreads();
  const int node0 = b * 256;
  const int k0 = bases[b], k1 = bases[b + 1];
  for (int k = k0 + t; k < k1; k += 256)
    atomicAdd(&sh[(int)(tmp[k] >> 16) - node0], 1);
  __syncthreads();
  const int v = sh[t];
  int inc2 = v;
#pragma unroll
  for (int o = 1; o < 64; o <<= 1) {
    int u = __shfl_up(inc2, o, 64);
    if (lane >= o) inc2 += u;
  }
  if (lane == 63) ws4[w] = inc2;
  __syncthreads();
  if (t == 0) {
    int run = 0;
#pragma unroll
    for (int k = 0; k < 4; ++k) { int vv = ws4[k]; ws4[k + 4] = run; run += vv; }
  }
  __syncthreads();
  const int excl = k0 + ws4[w + 4] + inc2 - v;
  if (node0 + t < N) {
    rp[node0 + t] = excl;
    dis[node0 + t] = rsqrtf((float)(v + 1));   // +1 = self loop
  }
  if (b == 0 && t == 0) rp[N] = E;
  sh2[t] = excl;
  __syncthreads();
  for (int k = k0 + t; k < k1; k += 256) {
    unsigned e = tmp[k];
    int dl = (int)(e >> 16) - node0;
    int pos = atomicAdd(&sh2[dl], 1);
    col[pos] = (u16)(e & 0xFFFFu);
  }
}

// ---------------- B-resident GEMM: C[M,Nt] = A[M,256] @ Bt[Nt,256]^T ---------
template <int BN>
__global__ __launch_bounds__(256) void gemm_bres(const u16* __restrict__ A,
                                                 const u16* __restrict__ Bt,
                                                 u16* __restrict__ C, int Nt) {
  constexpr int K = 256;
  constexpr int NJ = BN / 16;
  constexpr int CH = BN * K / 8;
  __shared__ __align__(16) u16 Bs[BN * K];

  const int tid = threadIdx.x, lane = tid & 63, w = tid >> 6;
  const int bm = blockIdx.x, bn = blockIdx.y;

#pragma unroll
  for (int i = 0; i < CH / 256; ++i) {
    int c = tid + i * 256;
    int ln = c & 63, t2 = c >> 6;
    int ks = t2 & 7, j = t2 >> 3;
    int row = j * 16 + (ln & 15);
    int kk = ks * 32 + (ln >> 4) * 8;
    async16(&Bs[(size_t)c * 8], Bt + (size_t)(bn * BN + row) * K + kk);
  }

  const int r16 = lane & 15, quad = lane >> 4;
  const int m0 = w * 32;

  const u16* Ap0 = A + (size_t)(bm * 128 + m0 + r16) * K + quad * 8;
  const u16* Ap1 = Ap0 + 16 * K;
  f16x8 aa0[8], aa1[8];
#pragma unroll
  for (int ks = 0; ks < 8; ++ks) {
    aa0[ks] = *(const f16x8*)(Ap0 + ks * 32);
    aa1[ks] = *(const f16x8*)(Ap1 + ks * 32);
  }

  f32x4 acc[2][NJ];
  const f32x4 fzero = {0.f, 0.f, 0.f, 0.f};
#pragma unroll
  for (int i = 0; i < 2; ++i)
#pragma unroll
    for (int j = 0; j < NJ; ++j) acc[i][j] = fzero;

  __syncthreads();

#pragma unroll
  for (int ks = 0; ks < 8; ++ks) {
#pragma unroll
    for (int j = 0; j < NJ; ++j) {
      f16x8 bf = *(const f16x8*)(&Bs[(size_t)((j * 8 + ks) * 64 + lane) * 8]);
      acc[0][j] = __builtin_amdgcn_mfma_f32_16x16x32_f16(aa0[ks], bf, acc[0][j], 0, 0, 0);
      acc[1][j] = __builtin_amdgcn_mfma_f32_16x16x32_f16(aa1[ks], bf, acc[1][j], 0, 0, 0);
    }
  }
#pragma unroll
  for (int i = 0; i < 2; ++i)
#pragma unroll
    for (int j = 0; j < NJ; ++j) {
      int gr = bm * 128 + m0 + i * 16 + quad * 4;   // C/D: col=lane&15, row=quad*4+r
      int gc = bn * BN + j * 16 + r16;
#pragma unroll
      for (int r = 0; r < 4; ++r)
        C[(size_t)(gr + r) * Nt + gc] = f2h(acc[i][j][r]);
    }
}

// ---------------- aggregation, d=256 (unchanged: at gather plateau) ----------
__global__ __launch_bounds__(256) void agg_d256(const u16* __restrict__ h,
                                                const int* __restrict__ rp,
                                                const u16* __restrict__ col,
                                                const float* __restrict__ dis,
                                                const float* __restrict__ bias,
                                                u16* __restrict__ out, int N) {
  const int wid = threadIdx.x >> 6, lane = threadIdx.x & 63;
  const int i = blockIdx.x * 4 + wid;
  if (i >= N) return;
  const int sub = lane >> 5;
  const int l32 = lane & 31;
  const int c8 = l32 * 8;
  const float di = dis[i];
  h2 acc[4];
  {
    uint4 sv = *(const uint4*)(h + (size_t)i * 256 + c8);
    const _Float16 w = (_Float16)(sub ? 0.f : di);
    const h2 ws = {w, w};
    acc[0] = __builtin_bit_cast(h2, sv.x) * ws;
    acc[1] = __builtin_bit_cast(h2, sv.y) * ws;
    acc[2] = __builtin_bit_cast(h2, sv.z) * ws;
    acc[3] = __builtin_bit_cast(h2, sv.w) * ws;
  }
  const int e1 = rp[i + 1];
  for (int base = rp[i]; base < e1; base += 64) {
    int me = base + lane;
    int s_l = 0; float d_l = 0.f;
    if (me < e1) { s_l = (int)col[me]; d_l = dis[s_l]; }
    const int cnt = min(64, e1 - base);
    const int cntR = (cnt + 7) & ~7;
    for (int t = 0; t < cntR; t += 8) {
      int sA = __shfl(s_l, t + sub, 64);      float dA = __shfl(d_l, t + sub, 64);
      int sB = __shfl(s_l, t + 2 + sub, 64);  float dB = __shfl(d_l, t + 2 + sub, 64);
      int sC = __shfl(s_l, t + 4 + sub, 64);  float dC = __shfl(d_l, t + 4 + sub, 64);
      int sD = __shfl(s_l, t + 6 + sub, 64);  float dD = __shfl(d_l, t + 6 + sub, 64);
      uint4 pA = *(const uint4*)(h + (size_t)sA * 256 + c8);
      uint4 pB = *(const uint4*)(h + (size_t)sB * 256 + c8);
      uint4 pC = *(const uint4*)(h + (size_t)sC * 256 + c8);
      uint4 pD = *(const uint4*)(h + (size_t)sD * 256 + c8);
      _Float16 hA = (_Float16)dA, hB = (_Float16)dB;
      _Float16 hC = (_Float16)dC, hD = (_Float16)dD;
      h2 wA = {hA, hA}, wB = {hB, hB}, wC = {hC, hC}, wD = {hD, hD};
      pkfma4(acc, wA, pA); pkfma4(acc, wB, pB);
      pkfma4(acc, wC, pC); pkfma4(acc, wD, pD);
    }
  }
  float a[8];
#pragma unroll
  for (int j = 0; j < 4; ++j) {
    a[2 * j] = (float)acc[j].x;
    a[2 * j + 1] = (float)acc[j].y;
  }
#pragma unroll
  for (int k = 0; k < 8; ++k) a[k] += __shfl_xor(a[k], 32, 64);
  if (sub == 0) {
    float4 b0 = *(const float4*)(bias + c8);
    float4 b1 = *(const float4*)(bias + c8 + 4);
    float r0 = fmaxf(di * a[0] + b0.x, 0.f), r1 = fmaxf(di * a[1] + b0.y, 0.f);
    float r2 = fmaxf(di * a[2] + b0.z, 0.f), r3 = fmaxf(di * a[3] + b0.w, 0.f);
    float r4 = fmaxf(di * a[4] + b1.x, 0.f), r5 = fmaxf(di * a[5] + b1.y, 0.f);
    float r6 = fmaxf(di * a[6] + b1.z, 0.f), r7 = fmaxf(di * a[7] + b1.w, 0.f);
    uint4 ov;
    ov.x = (unsigned)f2h(r0) | ((unsigned)f2h(r1) << 16);
    ov.y = (unsigned)f2h(r2) | ((unsigned)f2h(r3) << 16);
    ov.z = (unsigned)f2h(r4) | ((unsigned)f2h(r5) << 16);
    ov.w = (unsigned)f2h(r6) | ((unsigned)f2h(r7) << 16);
    *(uint4*)(out + (size_t)i * 256 + c8) = ov;
  }
}

// final layer: h f16 [N,64], out fp32 [N,64], fp32 acc. 4 loads deep.
__global__ __launch_bounds__(256) void agg_d64(const u16* __restrict__ h,
                                               const int* __restrict__ rp,
                                               const u16* __restrict__ col,
                                               const float* __restrict__ dis,
                                               const float* __restrict__ bias,
                                               float* __restrict__ out, int N) {
  const int wid = threadIdx.x >> 6, lane = threadIdx.x & 63;
  const int i = blockIdx.x * 4 + wid;
  if (i >= N) return;
  const int grp = lane >> 3;      // edge slot 0..7
  const int l8 = lane & 7;
  const int c8 = l8 * 8;
  const float di = dis[i];
  float a[8];
  {
    uint4 sv = *(const uint4*)(h + (size_t)i * 64 + c8);
    const float w = (grp == 0) ? di : 0.f;
    a[0] = w * h2f((u16)sv.x); a[1] = w * h2f((u16)(sv.x >> 16));
    a[2] = w * h2f((u16)sv.y); a[3] = w * h2f((u16)(sv.y >> 16));
    a[4] = w * h2f((u16)sv.z); a[5] = w * h2f((u16)(sv.z >> 16));
    a[6] = w * h2f((u16)sv.w); a[7] = w * h2f((u16)(sv.w >> 16));
  }
  const int e1 = rp[i + 1];
  for (int base = rp[i]; base < e1; base += 64) {
    int me = base + lane;
    int s_l = 0; float d_l = 0.f;
    if (me < e1) { s_l = (int)col[me]; d_l = dis[s_l]; }
    const int cnt = min(64, e1 - base);
    const int cntR = (cnt + 31) & ~31;
    for (int t = 0; t < cntR; t += 32) {   // 32 slots/iter, 4 loads deep
      int sA = __shfl(s_l, t + grp, 64);       float dA = __shfl(d_l, t + grp, 64);
      int sB = __shfl(s_l, t + 8 + grp, 64);   float dB = __shfl(d_l, t + 8 + grp, 64);
      int sC = __shfl(s_l, t + 16 + grp, 64);  float dC = __shfl(d_l, t + 16 + grp, 64);
      int sD = __shfl(s_l, t + 24 + grp, 64);  float dD = __shfl(d_l, t + 24 + grp, 64);
      uint4 pA = *(const uint4*)(h + (size_t)sA * 64 + c8);
      uint4 pB = *(const uint4*)(h + (size_t)sB * 64 + c8);
      uint4 pC = *(const uint4*)(h + (size_t)sC * 64 + c8);
      uint4 pD = *(const uint4*)(h + (size_t)sD * 64 + c8);
      fma8(a, dA, pA); fma8(a, dB, pB); fma8(a, dC, pC); fma8(a, dD, pD);
    }
  }
#pragma unroll
  for (int k = 0; k < 8; ++k) a[k] += __shfl_xor(a[k], 8, 64);
#pragma unroll
  for (int k = 0; k < 8; ++k) a[k] += __shfl_xor(a[k], 16, 64);
#pragma unroll
  for (int k = 0; k < 8; ++k) a[k] += __shfl_xor(a[k], 32, 64);
  if (lane < 8) {
    float4 b0 = *(const float4*)(bias + c8);
    float4 b1 = *(const float4*)(bias + c8 + 4);
    float4 o0, o1;
    o0.x = di * a[0] + b0.x; o0.y = di * a[1] + b0.y;
    o0.z = di * a[2] + b0.z; o0.w = di * a[3] + b0.w;
    o1.x = di * a[4] + b1.x; o1.y = di * a[5] + b1.y;
    o1.z = di * a[6] + b1.z; o1.w = di * a[7] + b1.w;
    *(float4*)(out + (size_t)i * 64 + c8) = o0;
    *(float4*)(out + (size_t)i * 64 + c8 + 4) = o1;
  }
}

// ---------------- launch ----------------
extern "C" void kernel_launch(void* const* d_in, const int* in_sizes, int n_in,
                              void* d_out, int out_size, void* d_ws, size_t ws_size,
                              hipStream_t stream) {
  if (n_in < 8) return;
  const float* x = (const float*)d_in[0];
  const void* eptr = d_in[1];
  const float* W1 = (const float*)d_in[2];
  const float* b1 = (const float*)d_in[3];
  const float* W2 = (const float*)d_in[4];
  const float* b2 = (const float*)d_in[5];
  const float* W3 = (const float*)d_in[6];
  const float* b3 = (const float*)d_in[7];
  float* out = (float*)d_out;

  const int DIN = 256, DH = 256;
  const int N = in_sizes[0] / DIN;       // 50000
  const int E = in_sizes[1] / 2;         // 800000
  const int DOUT = in_sizes[6] / DH;     // 64
  const int MT = (N + 127) / 128;        // 391
  const int Mpad = MT * 128;
  const int nbuck = (N + 255) >> 8;      // 196

  auto rnd = [](size_t b) { return (b + 255) & ~(size_t)255; };
  size_t required = 0;
  required += rnd((size_t)Mpad * DH * 2) * 2;        // xpad + hbuf
  required += rnd((size_t)E * 2);                    // col (u16)
  required += rnd((size_t)E * 4);                    // tmp (packed pairs)
  required += rnd((size_t)(N + 1) * 4);              // rp
  required += rnd((size_t)N * 4);                    // dis
  required += rnd((size_t)DIN * DH * 2);             // wt1
  required += rnd((size_t)DH * DH * 2);              // wt2
  required += rnd((size_t)DH * DOUT * 2);            // wt3
  required += rnd((size_t)256 * NCHUNK * 4) * 2;     // cnt + offs
  required += rnd((size_t)(nbuck + 1) * 4);          // bases
  required += 256;                                   // sync
  if (ws_size < required || N > 65536 || nbuck > 256 || nbuck < 1) {
    zero_f32<<<(out_size + 255) / 256, 256, 0, stream>>>(out, out_size);
    return;
  }

  char* ws = (char*)d_ws;
  size_t off0 = 0;
  auto alloc = [&](size_t bytes) {
    char* p = ws + off0;
    off0 = (off0 + bytes + 255) & ~(size_t)255;
    return p;
  };
  u16* xpad = (u16*)alloc((size_t)Mpad * DH * 2);
  u16* hbuf = (u16*)alloc((size_t)Mpad * DH * 2);
  u16* colb = (u16*)alloc((size_t)E * 2);
  unsigned* tmpb = (unsigned*)alloc((size_t)E * 4);
  int* rp = (int*)alloc((size_t)(N + 1) * 4);
  float* dis = (float*)alloc((size_t)N * 4);
  u16* wt1 = (u16*)alloc((size_t)DIN * DH * 2);
  u16* wt2 = (u16*)alloc((size_t)DH * DH * 2);
  u16* wt3 = (u16*)alloc((size_t)DH * DOUT * 2);
  int* cnt = (int*)alloc((size_t)256 * NCHUNK * 4);
  int* offs = (int*)alloc((size_t)256 * NCHUNK * 4);
  int* bases = (int*)alloc((size_t)(nbuck + 1) * 4);
  int* syncp = (int*)alloc(256);

  const int n_tot4 = Mpad * DH / 4;
  const int nb_cvt = (n_tot4 + 255) / 256;
  const int nb_w1 = (DIN * DH + 255) / 256;
  const int nb_w2 = (DH * DH + 255) / 256;
  const int nb_w3 = (DH * DOUT + 255) / 256;
  prep_all<<<nb_cvt + nb_w1 + nb_w2 + nb_w3 + NCHUNK + 1, 256, 0, stream>>>(
      (const float4*)x, (ushort4*)xpad, N * DH / 4, n_tot4,
      W1, wt1, W2, wt2, W3, wt3, eptr, cnt, syncp,
      E, N, DIN, DH, DOUT, nb_cvt, nb_w1, nb_w2, nb_w3);

  const int gcsr = (nbuck > NCHUNK) ? nbuck : NCHUNK;
  csr_all<<<gcsr, 256, 0, stream>>>(eptr, cnt, bases, offs, tmpb, rp, dis, colb,
                                    syncp, E, N, nbuck);

  // layer 1
  gemm_bres<128><<<dim3(MT, DH / 128), 256, 0, stream>>>(xpad, wt1, hbuf, DH);
  agg_d256<<<(N + 3) / 4, 256, 0, stream>>>(hbuf, rp, colb, dis, b1, xpad, N);
  // layer 2
  gemm_bres<128><<<dim3(MT, DH / 128), 256, 0, stream>>>(xpad, wt2, hbuf, DH);
  agg_d256<<<(N + 3) / 4, 256, 0, stream>>>(hbuf, rp, colb, dis, b2, xpad, N);
  // layer 3
  gemm_bres<64><<<dim3(MT, DOUT / 64), 256, 0, stream>>>(xpad, wt3, hbuf, DOUT);
  agg_d64<<<(N + 3) / 4, 256, 0, stream>>>(hbuf, rp, colb, dis, b3, out, N);
}

// Round 12
// 359.166 us; speedup vs baseline: 1.3108x; 1.3108x over previous
//
#include <hip/hip_runtime.h>
#include <cstdint>
#include <cstddef>

typedef unsigned short u16;
typedef _Float16 f16x8 __attribute__((ext_vector_type(8)));
typedef _Float16 h2 __attribute__((ext_vector_type(2)));
typedef float f32x4 __attribute__((ext_vector_type(4)));

__device__ __forceinline__ float h2f(u16 u) {
  return (float)__builtin_bit_cast(_Float16, u);
}
__device__ __forceinline__ u16 f2h(float f) {
  return __builtin_bit_cast(u16, (_Float16)f);
}

// async 16B global -> LDS (gfx950)
__device__ __forceinline__ void async16(u16* lds, const u16* g) {
  __builtin_amdgcn_global_load_lds(
      (const __attribute__((address_space(1))) unsigned int*)g,
      (__attribute__((address_space(3))) unsigned int*)lds, 16, 0, 0);
}

// fp32 unpack-fma (final layer, fp32 accumulation)
__device__ __forceinline__ void fma8(float* a, float d, uint4 p) {
  a[0] += d * h2f((u16)p.x); a[1] += d * h2f((u16)(p.x >> 16));
  a[2] += d * h2f((u16)p.y); a[3] += d * h2f((u16)(p.y >> 16));
  a[4] += d * h2f((u16)p.z); a[5] += d * h2f((u16)(p.z >> 16));
  a[6] += d * h2f((u16)p.w); a[7] += d * h2f((u16)(p.w >> 16));
}

// packed f16 fma: acc[j] += h2(p word j) * w
__device__ __forceinline__ void pkfma4(h2* acc, h2 w, uint4 p) {
  acc[0] += __builtin_bit_cast(h2, p.x) * w;
  acc[1] += __builtin_bit_cast(h2, p.y) * w;
  acc[2] += __builtin_bit_cast(h2, p.z) * w;
  acc[3] += __builtin_bit_cast(h2, p.w) * w;
}

// per-wave int64-vs-int32 edge dtype detection (first 1KB, L2-hot)
__device__ __forceinline__ int wave_is64(const void* ep) {
  const unsigned* p = (const unsigned*)ep;
  const int lane = threadIdx.x & 63;
  unsigned v = p[2 * lane + 1] | p[2 * (lane + 64) + 1];
  unsigned long long bal = __ballot(v != 0u);
  return (bal == 0ull) ? 1 : 0;
}

__device__ __forceinline__ int edge_at(const void* ep, int is64, long long idx) {
  if (is64) return (int)((const long long*)ep)[idx];
  return ((const int*)ep)[idx];
}

#define NCHUNK 64

// ---------------- diagnostics / fallback ----------------
__global__ void zero_f32(float* p, int n) {
  int i = blockIdx.x * 256 + threadIdx.x;
  if (i < n) p[i] = 0.f;
}

// ---------------- prep_all: cvt_pad + 3x transpose_w + csr_hist ----------------
__global__ __launch_bounds__(256) void prep_all(
    const float4* __restrict__ x, ushort4* __restrict__ xpad, int n_src4, int n_tot4,
    const float* __restrict__ W1, u16* __restrict__ wt1,
    const float* __restrict__ W2, u16* __restrict__ wt2,
    const float* __restrict__ W3, u16* __restrict__ wt3,
    const void* __restrict__ ep, int* __restrict__ cnt,
    int E, int N, int DIN, int DH, int DOUT,
    int nb_cvt, int nb_w1, int nb_w2, int nb_w3) {
  int b = blockIdx.x;
  if (b < nb_cvt) {                       // fp32 -> f16 convert + pad
    int i = b * 256 + threadIdx.x;
    if (i < n_tot4) {
      ushort4 o = {0, 0, 0, 0};
      if (i < n_src4) {
        float4 v = x[i];
        o.x = f2h(v.x); o.y = f2h(v.y); o.z = f2h(v.z); o.w = f2h(v.w);
      }
      xpad[i] = o;
    }
    return;
  }
  b -= nb_cvt;
  if (b < nb_w1) {                        // wt1[n*DIN+k] = W1[k*DH+n]
    int idx = b * 256 + threadIdx.x;
    if (idx < DIN * DH) {
      int n = idx / DIN, k = idx % DIN;
      wt1[idx] = f2h(W1[k * DH + n]);
    }
    return;
  }
  b -= nb_w1;
  if (b < nb_w2) {                        // wt2[n*DH+k] = W2[k*DH+n]
    int idx = b * 256 + threadIdx.x;
    if (idx < DH * DH) {
      int n = idx / DH, k = idx % DH;
      wt2[idx] = f2h(W2[k * DH + n]);
    }
    return;
  }
  b -= nb_w2;
  if (b < nb_w3) {                        // wt3[n*DH+k] = W3[k*DOUT+n]
    int idx = b * 256 + threadIdx.x;
    if (idx < DH * DOUT) {
      int n = idx / DH, k = idx % DH;
      wt3[idx] = f2h(W3[k * DOUT + n]);
    }
    return;
  }
  b -= nb_w3;
  {                                       // per-chunk bucket histogram
    __shared__ int h[256];
    h[threadIdx.x] = 0;
    __syncthreads();
    int is64 = wave_is64(ep);
    const int per = (E + NCHUNK - 1) / NCHUNK;
    const int e0 = b * per, e1 = min(e0 + per, E);
    for (int e = e0 + (int)threadIdx.x; e < e1; e += 256) {
      int d = edge_at(ep, is64, (long long)E + e);
      d = min(max(d, 0), N - 1);
      atomicAdd(&h[d >> 8], 1);
    }
    __syncthreads();
    cnt[threadIdx.x * NCHUNK + b] = h[threadIdx.x];
  }
}

// ---------------- bucketed CSR build, separate kernels (R10-proven) ----------
__global__ __launch_bounds__(256) void csr_base(const int* __restrict__ cnt,
                                                int* __restrict__ bases,
                                                int* __restrict__ off,
                                                int nbuck, int E) {
  __shared__ int ws4[8];
  const int t = threadIdx.x, lane = t & 63, w = t >> 6;
  int tot = 0;
  if (t < nbuck)
#pragma unroll 8
    for (int c = 0; c < NCHUNK; ++c) tot += cnt[t * NCHUNK + c];
  int inc = tot;
#pragma unroll
  for (int o = 1; o < 64; o <<= 1) {
    int u = __shfl_up(inc, o, 64);
    if (lane >= o) inc += u;
  }
  if (lane == 63) ws4[w] = inc;
  __syncthreads();
  if (t == 0) {
    int run = 0;
#pragma unroll
    for (int k = 0; k < 4; ++k) { int v = ws4[k]; ws4[k + 4] = run; run += v; }
  }
  __syncthreads();
  const int base = ws4[w + 4] + inc - tot;
  if (t < nbuck) {
    bases[t] = base;
    int run = base;
    for (int c = 0; c < NCHUNK; ++c) {
      off[t * NCHUNK + c] = run;
      run += cnt[t * NCHUNK + c];
    }
  }
  if (t == 0) bases[nbuck] = E;
}

__global__ __launch_bounds__(256) void csr_bucket(const void* __restrict__ ep,
                                                  const int* __restrict__ off,
                                                  unsigned* __restrict__ tmp,
                                                  int E, int N) {
  __shared__ int cur[256];
  const int chunk = blockIdx.x;
  const int nbuck = (N + 255) >> 8;
  if ((int)threadIdx.x < nbuck) cur[threadIdx.x] = off[threadIdx.x * NCHUNK + chunk];
  __syncthreads();
  int is64 = wave_is64(ep);
  const int per = (E + NCHUNK - 1) / NCHUNK;
  const int e0 = chunk * per, e1 = min(e0 + per, E);
  for (int e = e0 + (int)threadIdx.x; e < e1; e += 256) {
    int s = edge_at(ep, is64, e);
    int d = edge_at(ep, is64, (long long)E + e);
    s = min(max(s, 0), N - 1);
    d = min(max(d, 0), N - 1);
    int pos = atomicAdd(&cur[d >> 8], 1);
    tmp[pos] = ((unsigned)d << 16) | (unsigned)s;
  }
}

__global__ __launch_bounds__(256) void csr_final(const unsigned* __restrict__ tmp,
                                                 const int* __restrict__ bases,
                                                 int* __restrict__ rp,
                                                 float* __restrict__ dis,
                                                 u16* __restrict__ col, int N, int E) {
  __shared__ int hcnt[256];
  __shared__ int curs[256];
  __shared__ int ws4[8];
  const int b = blockIdx.x;
  const int node0 = b * 256;
  const int t = threadIdx.x, lane = t & 63, w = t >> 6;
  hcnt[t] = 0;
  __syncthreads();
  const int k0 = bases[b];
  const int k1 = bases[b + 1];
  for (int k = k0 + t; k < k1; k += 256)
    atomicAdd(&hcnt[(int)(tmp[k] >> 16) - node0], 1);
  __syncthreads();
  const int v = hcnt[t];
  int inc = v;
#pragma unroll
  for (int o = 1; o < 64; o <<= 1) {
    int u = __shfl_up(inc, o, 64);
    if (lane >= o) inc += u;
  }
  if (lane == 63) ws4[w] = inc;
  __syncthreads();
  if (t == 0) {
    int run = 0;
#pragma unroll
    for (int k = 0; k < 4; ++k) { int vv = ws4[k]; ws4[k + 4] = run; run += vv; }
  }
  __syncthreads();
  const int excl = k0 + ws4[w + 4] + inc - v;
  if (node0 + t < N) {
    rp[node0 + t] = excl;
    dis[node0 + t] = rsqrtf((float)(v + 1));   // +1 = self loop
  }
  if (b == 0 && t == 0) rp[N] = E;
  curs[t] = excl;
  __syncthreads();
  for (int k = k0 + t; k < k1; k += 256) {
    unsigned e = tmp[k];
    int dl = (int)(e >> 16) - node0;
    int pos = atomicAdd(&curs[dl], 1);
    col[pos] = (u16)(e & 0xFFFFu);
  }
}

// ---------------- B-resident GEMM: C[M,Nt] = A[M,256] @ Bt[Nt,256]^T ---------
template <int BN>
__global__ __launch_bounds__(256) void gemm_bres(const u16* __restrict__ A,
                                                 const u16* __restrict__ Bt,
                                                 u16* __restrict__ C, int Nt) {
  constexpr int K = 256;
  constexpr int NJ = BN / 16;
  constexpr int CH = BN * K / 8;
  __shared__ __align__(16) u16 Bs[BN * K];

  const int tid = threadIdx.x, lane = tid & 63, w = tid >> 6;
  const int bm = blockIdx.x, bn = blockIdx.y;

#pragma unroll
  for (int i = 0; i < CH / 256; ++i) {
    int c = tid + i * 256;
    int ln = c & 63, t2 = c >> 6;
    int ks = t2 & 7, j = t2 >> 3;
    int row = j * 16 + (ln & 15);
    int kk = ks * 32 + (ln >> 4) * 8;
    async16(&Bs[(size_t)c * 8], Bt + (size_t)(bn * BN + row) * K + kk);
  }

  const int r16 = lane & 15, quad = lane >> 4;
  const int m0 = w * 32;

  const u16* Ap0 = A + (size_t)(bm * 128 + m0 + r16) * K + quad * 8;
  const u16* Ap1 = Ap0 + 16 * K;
  f16x8 aa0[8], aa1[8];
#pragma unroll
  for (int ks = 0; ks < 8; ++ks) {
    aa0[ks] = *(const f16x8*)(Ap0 + ks * 32);
    aa1[ks] = *(const f16x8*)(Ap1 + ks * 32);
  }

  f32x4 acc[2][NJ];
  const f32x4 fzero = {0.f, 0.f, 0.f, 0.f};
#pragma unroll
  for (int i = 0; i < 2; ++i)
#pragma unroll
    for (int j = 0; j < NJ; ++j) acc[i][j] = fzero;

  __syncthreads();

#pragma unroll
  for (int ks = 0; ks < 8; ++ks) {
#pragma unroll
    for (int j = 0; j < NJ; ++j) {
      f16x8 bf = *(const f16x8*)(&Bs[(size_t)((j * 8 + ks) * 64 + lane) * 8]);
      acc[0][j] = __builtin_amdgcn_mfma_f32_16x16x32_f16(aa0[ks], bf, acc[0][j], 0, 0, 0);
      acc[1][j] = __builtin_amdgcn_mfma_f32_16x16x32_f16(aa1[ks], bf, acc[1][j], 0, 0, 0);
    }
  }
#pragma unroll
  for (int i = 0; i < 2; ++i)
#pragma unroll
    for (int j = 0; j < NJ; ++j) {
      int gr = bm * 128 + m0 + i * 16 + quad * 4;   // C/D: col=lane&15, row=quad*4+r
      int gc = bn * BN + j * 16 + r16;
#pragma unroll
      for (int r = 0; r < 4; ++r)
        C[(size_t)(gr + r) * Nt + gc] = f2h(acc[i][j][r]);
    }
}

// ---------------- aggregation, d=256 (at gather plateau) ----------
__global__ __launch_bounds__(256) void agg_d256(const u16* __restrict__ h,
                                                const int* __restrict__ rp,
                                                const u16* __restrict__ col,
                                                const float* __restrict__ dis,
                                                const float* __restrict__ bias,
                                                u16* __restrict__ out, int N) {
  const int wid = threadIdx.x >> 6, lane = threadIdx.x & 63;
  const int i = blockIdx.x * 4 + wid;
  if (i >= N) return;
  const int sub = lane >> 5;
  const int l32 = lane & 31;
  const int c8 = l32 * 8;
  const float di = dis[i];
  h2 acc[4];
  {
    uint4 sv = *(const uint4*)(h + (size_t)i * 256 + c8);
    const _Float16 w = (_Float16)(sub ? 0.f : di);
    const h2 ws = {w, w};
    acc[0] = __builtin_bit_cast(h2, sv.x) * ws;
    acc[1] = __builtin_bit_cast(h2, sv.y) * ws;
    acc[2] = __builtin_bit_cast(h2, sv.z) * ws;
    acc[3] = __builtin_bit_cast(h2, sv.w) * ws;
  }
  const int e1 = rp[i + 1];
  for (int base = rp[i]; base < e1; base += 64) {
    int me = base + lane;
    int s_l = 0; float d_l = 0.f;
    if (me < e1) { s_l = (int)col[me]; d_l = dis[s_l]; }
    const int cnt = min(64, e1 - base);
    const int cntR = (cnt + 7) & ~7;
    for (int t = 0; t < cntR; t += 8) {
      int sA = __shfl(s_l, t + sub, 64);      float dA = __shfl(d_l, t + sub, 64);
      int sB = __shfl(s_l, t + 2 + sub, 64);  float dB = __shfl(d_l, t + 2 + sub, 64);
      int sC = __shfl(s_l, t + 4 + sub, 64);  float dC = __shfl(d_l, t + 4 + sub, 64);
      int sD = __shfl(s_l, t + 6 + sub, 64);  float dD = __shfl(d_l, t + 6 + sub, 64);
      uint4 pA = *(const uint4*)(h + (size_t)sA * 256 + c8);
      uint4 pB = *(const uint4*)(h + (size_t)sB * 256 + c8);
      uint4 pC = *(const uint4*)(h + (size_t)sC * 256 + c8);
      uint4 pD = *(const uint4*)(h + (size_t)sD * 256 + c8);
      _Float16 hA = (_Float16)dA, hB = (_Float16)dB;
      _Float16 hC = (_Float16)dC, hD = (_Float16)dD;
      h2 wA = {hA, hA}, wB = {hB, hB}, wC = {hC, hC}, wD = {hD, hD};
      pkfma4(acc, wA, pA); pkfma4(acc, wB, pB);
      pkfma4(acc, wC, pC); pkfma4(acc, wD, pD);
    }
  }
  float a[8];
#pragma unroll
  for (int j = 0; j < 4; ++j) {
    a[2 * j] = (float)acc[j].x;
    a[2 * j + 1] = (float)acc[j].y;
  }
#pragma unroll
  for (int k = 0; k < 8; ++k) a[k] += __shfl_xor(a[k], 32, 64);
  if (sub == 0) {
    float4 b0 = *(const float4*)(bias + c8);
    float4 b1 = *(const float4*)(bias + c8 + 4);
    float r0 = fmaxf(di * a[0] + b0.x, 0.f), r1 = fmaxf(di * a[1] + b0.y, 0.f);
    float r2 = fmaxf(di * a[2] + b0.z, 0.f), r3 = fmaxf(di * a[3] + b0.w, 0.f);
    float r4 = fmaxf(di * a[4] + b1.x, 0.f), r5 = fmaxf(di * a[5] + b1.y, 0.f);
    float r6 = fmaxf(di * a[6] + b1.z, 0.f), r7 = fmaxf(di * a[7] + b1.w, 0.f);
    uint4 ov;
    ov.x = (unsigned)f2h(r0) | ((unsigned)f2h(r1) << 16);
    ov.y = (unsigned)f2h(r2) | ((unsigned)f2h(r3) << 16);
    ov.z = (unsigned)f2h(r4) | ((unsigned)f2h(r5) << 16);
    ov.w = (unsigned)f2h(r6) | ((unsigned)f2h(r7) << 16);
    *(uint4*)(out + (size_t)i * 256 + c8) = ov;
  }
}

// final layer: h f16 [N,64], out fp32 [N,64], fp32 acc. 4 loads deep.
__global__ __launch_bounds__(256) void agg_d64(const u16* __restrict__ h,
                                               const int* __restrict__ rp,
                                               const u16* __restrict__ col,
                                               const float* __restrict__ dis,
                                               const float* __restrict__ bias,
                                               float* __restrict__ out, int N) {
  const int wid = threadIdx.x >> 6, lane = threadIdx.x & 63;
  const int i = blockIdx.x * 4 + wid;
  if (i >= N) return;
  const int grp = lane >> 3;      // edge slot 0..7
  const int l8 = lane & 7;
  const int c8 = l8 * 8;
  const float di = dis[i];
  float a[8];
  {
    uint4 sv = *(const uint4*)(h + (size_t)i * 64 + c8);
    const float w = (grp == 0) ? di : 0.f;
    a[0] = w * h2f((u16)sv.x); a[1] = w * h2f((u16)(sv.x >> 16));
    a[2] = w * h2f((u16)sv.y); a[3] = w * h2f((u16)(sv.y >> 16));
    a[4] = w * h2f((u16)sv.z); a[5] = w * h2f((u16)(sv.z >> 16));
    a[6] = w * h2f((u16)sv.w); a[7] = w * h2f((u16)(sv.w >> 16));
  }
  const int e1 = rp[i + 1];
  for (int base = rp[i]; base < e1; base += 64) {
    int me = base + lane;
    int s_l = 0; float d_l = 0.f;
    if (me < e1) { s_l = (int)col[me]; d_l = dis[s_l]; }
    const int cnt = min(64, e1 - base);
    const int cntR = (cnt + 31) & ~31;
    for (int t = 0; t < cntR; t += 32) {   // 32 slots/iter, 4 loads deep
      int sA = __shfl(s_l, t + grp, 64);       float dA = __shfl(d_l, t + grp, 64);
      int sB = __shfl(s_l, t + 8 + grp, 64);   float dB = __shfl(d_l, t + 8 + grp, 64);
      int sC = __shfl(s_l, t + 16 + grp, 64);  float dC = __shfl(d_l, t + 16 + grp, 64);
      int sD = __shfl(s_l, t + 24 + grp, 64);  float dD = __shfl(d_l, t + 24 + grp, 64);
      uint4 pA = *(const uint4*)(h + (size_t)sA * 64 + c8);
      uint4 pB = *(const uint4*)(h + (size_t)sB * 64 + c8);
      uint4 pC = *(const uint4*)(h + (size_t)sC * 64 + c8);
      uint4 pD = *(const uint4*)(h + (size_t)sD * 64 + c8);
      fma8(a, dA, pA); fma8(a, dB, pB); fma8(a, dC, pC); fma8(a, dD, pD);
    }
  }
#pragma unroll
  for (int k = 0; k < 8; ++k) a[k] += __shfl_xor(a[k], 8, 64);
#pragma unroll
  for (int k = 0; k < 8; ++k) a[k] += __shfl_xor(a[k], 16, 64);
#pragma unroll
  for (int k = 0; k < 8; ++k) a[k] += __shfl_xor(a[k], 32, 64);
  if (lane < 8) {
    float4 b0 = *(const float4*)(bias + c8);
    float4 b1 = *(const float4*)(bias + c8 + 4);
    float4 o0, o1;
    o0.x = di * a[0] + b0.x; o0.y = di * a[1] + b0.y;
    o0.z = di * a[2] + b0.z; o0.w = di * a[3] + b0.w;
    o1.x = di * a[4] + b1.x; o1.y = di * a[5] + b1.y;
    o1.z = di * a[6] + b1.z; o1.w = di * a[7] + b1.w;
    *(float4*)(out + (size_t)i * 64 + c8) = o0;
    *(float4*)(out + (size_t)i * 64 + c8 + 4) = o1;
  }
}

// ---------------- launch ----------------
extern "C" void kernel_launch(void* const* d_in, const int* in_sizes, int n_in,
                              void* d_out, int out_size, void* d_ws, size_t ws_size,
                              hipStream_t stream) {
  if (n_in < 8) return;
  const float* x = (const float*)d_in[0];
  const void* eptr = d_in[1];
  const float* W1 = (const float*)d_in[2];
  const float* b1 = (const float*)d_in[3];
  const float* W2 = (const float*)d_in[4];
  const float* b2 = (const float*)d_in[5];
  const float* W3 = (const float*)d_in[6];
  const float* b3 = (const float*)d_in[7];
  float* out = (float*)d_out;

  const int DIN = 256, DH = 256;
  const int N = in_sizes[0] / DIN;       // 50000
  const int E = in_sizes[1] / 2;         // 800000
  const int DOUT = in_sizes[6] / DH;     // 64
  const int MT = (N + 127) / 128;        // 391
  const int Mpad = MT * 128;
  const int nbuck = (N + 255) >> 8;      // 196

  auto rnd = [](size_t b) { return (b + 255) & ~(size_t)255; };
  size_t required = 0;
  required += rnd((size_t)Mpad * DH * 2) * 2;        // xpad + hbuf
  required += rnd((size_t)E * 2);                    // col (u16)
  required += rnd((size_t)E * 4);                    // tmp (packed pairs)
  required += rnd((size_t)(N + 1) * 4);              // rp
  required += rnd((size_t)N * 4);                    // dis
  required += rnd((size_t)DIN * DH * 2);             // wt1
  required += rnd((size_t)DH * DH * 2);              // wt2
  required += rnd((size_t)DH * DOUT * 2);            // wt3
  required += rnd((size_t)256 * NCHUNK * 4) * 2;     // cnt + offs
  required += rnd((size_t)(nbuck + 1) * 4);          // bases
  if (ws_size < required || N > 65536 || nbuck > 256 || nbuck < 1) {
    zero_f32<<<(out_size + 255) / 256, 256, 0, stream>>>(out, out_size);
    return;
  }

  char* ws = (char*)d_ws;
  size_t off0 = 0;
  auto alloc = [&](size_t bytes) {
    char* p = ws + off0;
    off0 = (off0 + bytes + 255) & ~(size_t)255;
    return p;
  };
  u16* xpad = (u16*)alloc((size_t)Mpad * DH * 2);
  u16* hbuf = (u16*)alloc((size_t)Mpad * DH * 2);
  u16* colb = (u16*)alloc((size_t)E * 2);
  unsigned* tmpb = (unsigned*)alloc((size_t)E * 4);
  int* rp = (int*)alloc((size_t)(N + 1) * 4);
  float* dis = (float*)alloc((size_t)N * 4);
  u16* wt1 = (u16*)alloc((size_t)DIN * DH * 2);
  u16* wt2 = (u16*)alloc((size_t)DH * DH * 2);
  u16* wt3 = (u16*)alloc((size_t)DH * DOUT * 2);
  int* cnt = (int*)alloc((size_t)256 * NCHUNK * 4);
  int* offs = (int*)alloc((size_t)256 * NCHUNK * 4);
  int* bases = (int*)alloc((size_t)(nbuck + 1) * 4);

  const int n_tot4 = Mpad * DH / 4;
  const int nb_cvt = (n_tot4 + 255) / 256;
  const int nb_w1 = (DIN * DH + 255) / 256;
  const int nb_w2 = (DH * DH + 255) / 256;
  const int nb_w3 = (DH * DOUT + 255) / 256;
  prep_all<<<nb_cvt + nb_w1 + nb_w2 + nb_w3 + NCHUNK, 256, 0, stream>>>(
      (const float4*)x, (ushort4*)xpad, N * DH / 4, n_tot4,
      W1, wt1, W2, wt2, W3, wt3, eptr, cnt,
      E, N, DIN, DH, DOUT, nb_cvt, nb_w1, nb_w2, nb_w3);

  csr_base<<<1, 256, 0, stream>>>(cnt, bases, offs, nbuck, E);
  csr_bucket<<<NCHUNK, 256, 0, stream>>>(eptr, offs, tmpb, E, N);
  csr_final<<<nbuck, 256, 0, stream>>>(tmpb, bases, rp, dis, colb, N, E);

  // layer 1
  gemm_bres<128><<<dim3(MT, DH / 128), 256, 0, stream>>>(xpad, wt1, hbuf, DH);
  agg_d256<<<(N + 3) / 4, 256, 0, stream>>>(hbuf, rp, colb, dis, b1, xpad, N);
  // layer 2
  gemm_bres<128><<<dim3(MT, DH / 128), 256, 0, stream>>>(xpad, wt2, hbuf, DH);
  agg_d256<<<(N + 3) / 4, 256, 0, stream>>>(hbuf, rp, colb, dis, b2, xpad, N);
  // layer 3
  gemm_bres<64><<<dim3(MT, DOUT / 64), 256, 0, stream>>>(xpad, wt3, hbuf, DOUT);
  agg_d64<<<(N + 3) / 4, 256, 0, stream>>>(hbuf, rp, colb, dis, b3, out, N);
}

// Round 13
// 302.120 us; speedup vs baseline: 1.5583x; 1.1888x over previous
//
#include <hip/hip_runtime.h>
#include <hip/hip_fp8.h>
#include <cstdint>
#include <cstddef>

typedef unsigned short u16;
typedef _Float16 f16x8 __attribute__((ext_vector_type(8)));
typedef float f32x2 __attribute__((ext_vector_type(2)));
typedef float f32x4 __attribute__((ext_vector_type(4)));

#if defined(__has_builtin)
#if __has_builtin(__builtin_amdgcn_cvt_pk_f32_fp8) && __has_builtin(__builtin_amdgcn_cvt_pk_fp8_f32)
#define FP8_BUILTIN 1
#endif
#endif

__device__ __forceinline__ float h2f(u16 u) {
  return (float)__builtin_bit_cast(_Float16, u);
}
__device__ __forceinline__ u16 f2h(float f) {
  return __builtin_bit_cast(u16, (_Float16)f);
}
__device__ __forceinline__ unsigned char ftofp8(float f) {
#ifdef FP8_BUILTIN
  return (unsigned char)(__builtin_amdgcn_cvt_pk_fp8_f32(f, f, 0, false) & 0xFF);
#else
  return __hip_fp8_e4m3(f).__x;
#endif
}

// async 16B global -> LDS (gfx950)
__device__ __forceinline__ void async16(u16* lds, const u16* g) {
  __builtin_amdgcn_global_load_lds(
      (const __attribute__((address_space(1))) unsigned int*)g,
      (__attribute__((address_space(3))) unsigned int*)lds, 16, 0, 0);
}

// fp32 unpack-fma from f16 pairs (final layer)
__device__ __forceinline__ void fma8(float* a, float d, uint4 p) {
  a[0] += d * h2f((u16)p.x); a[1] += d * h2f((u16)(p.x >> 16));
  a[2] += d * h2f((u16)p.y); a[3] += d * h2f((u16)(p.y >> 16));
  a[4] += d * h2f((u16)p.z); a[5] += d * h2f((u16)(p.z >> 16));
  a[6] += d * h2f((u16)p.w); a[7] += d * h2f((u16)(p.w >> 16));
}

// fp8 row chunk (8 bytes) -> fp32 fma
__device__ __forceinline__ void fma8p(float* a, float d, uint2 p) {
#ifdef FP8_BUILTIN
  f32x2 v0 = __builtin_amdgcn_cvt_pk_f32_fp8((int)p.x, false);
  f32x2 v1 = __builtin_amdgcn_cvt_pk_f32_fp8((int)p.x, true);
  f32x2 v2 = __builtin_amdgcn_cvt_pk_f32_fp8((int)p.y, false);
  f32x2 v3 = __builtin_amdgcn_cvt_pk_f32_fp8((int)p.y, true);
  a[0] += d * v0.x; a[1] += d * v0.y; a[2] += d * v1.x; a[3] += d * v1.y;
  a[4] += d * v2.x; a[5] += d * v2.y; a[6] += d * v3.x; a[7] += d * v3.y;
#else
  const unsigned char* b = (const unsigned char*)&p;
#pragma unroll
  for (int k = 0; k < 8; ++k) {
    __hip_fp8_e4m3 v; v.__x = b[k];
    a[k] += d * (float)v;
  }
#endif
}

// per-wave int64-vs-int32 edge dtype detection (first 1KB, L2-hot)
__device__ __forceinline__ int wave_is64(const void* ep) {
  const unsigned* p = (const unsigned*)ep;
  const int lane = threadIdx.x & 63;
  unsigned v = p[2 * lane + 1] | p[2 * (lane + 64) + 1];
  unsigned long long bal = __ballot(v != 0u);
  return (bal == 0ull) ? 1 : 0;
}

__device__ __forceinline__ int edge_at(const void* ep, int is64, long long idx) {
  if (is64) return (int)((const long long*)ep)[idx];
  return ((const int*)ep)[idx];
}

#define NCHUNK 64

// ---------------- diagnostics / fallback ----------------
__global__ void zero_f32(float* p, int n) {
  int i = blockIdx.x * 256 + threadIdx.x;
  if (i < n) p[i] = 0.f;
}

// ---------------- prep_all: cvt_pad + 3x transpose_w + csr_hist ----------------
__global__ __launch_bounds__(256) void prep_all(
    const float4* __restrict__ x, ushort4* __restrict__ xpad, int n_src4, int n_tot4,
    const float* __restrict__ W1, u16* __restrict__ wt1,
    const float* __restrict__ W2, u16* __restrict__ wt2,
    const float* __restrict__ W3, u16* __restrict__ wt3,
    const void* __restrict__ ep, int* __restrict__ cnt,
    int E, int N, int DIN, int DH, int DOUT,
    int nb_cvt, int nb_w1, int nb_w2, int nb_w3) {
  int b = blockIdx.x;
  if (b < nb_cvt) {                       // fp32 -> f16 convert + pad
    int i = b * 256 + threadIdx.x;
    if (i < n_tot4) {
      ushort4 o = {0, 0, 0, 0};
      if (i < n_src4) {
        float4 v = x[i];
        o.x = f2h(v.x); o.y = f2h(v.y); o.z = f2h(v.z); o.w = f2h(v.w);
      }
      xpad[i] = o;
    }
    return;
  }
  b -= nb_cvt;
  if (b < nb_w1) {                        // wt1[n*DIN+k] = W1[k*DH+n]
    int idx = b * 256 + threadIdx.x;
    if (idx < DIN * DH) {
      int n = idx / DIN, k = idx % DIN;
      wt1[idx] = f2h(W1[k * DH + n]);
    }
    return;
  }
  b -= nb_w1;
  if (b < nb_w2) {                        // wt2[n*DH+k] = W2[k*DH+n]
    int idx = b * 256 + threadIdx.x;
    if (idx < DH * DH) {
      int n = idx / DH, k = idx % DH;
      wt2[idx] = f2h(W2[k * DH + n]);
    }
    return;
  }
  b -= nb_w2;
  if (b < nb_w3) {                        // wt3[n*DH+k] = W3[k*DOUT+n]
    int idx = b * 256 + threadIdx.x;
    if (idx < DH * DOUT) {
      int n = idx / DH, k = idx % DH;
      wt3[idx] = f2h(W3[k * DOUT + n]);
    }
    return;
  }
  b -= nb_w3;
  {                                       // per-chunk bucket histogram
    __shared__ int h[256];
    h[threadIdx.x] = 0;
    __syncthreads();
    int is64 = wave_is64(ep);
    const int per = (E + NCHUNK - 1) / NCHUNK;
    const int e0 = b * per, e1 = min(e0 + per, E);
    for (int e = e0 + (int)threadIdx.x; e < e1; e += 256) {
      int d = edge_at(ep, is64, (long long)E + e);
      d = min(max(d, 0), N - 1);
      atomicAdd(&h[d >> 8], 1);
    }
    __syncthreads();
    cnt[threadIdx.x * NCHUNK + b] = h[threadIdx.x];
  }
}

// ---------------- bucketed CSR build (R10-proven separate kernels) ----------
__global__ __launch_bounds__(256) void csr_base(const int* __restrict__ cnt,
                                                int* __restrict__ bases,
                                                int* __restrict__ off,
                                                int nbuck, int E) {
  __shared__ int ws4[8];
  const int t = threadIdx.x, lane = t & 63, w = t >> 6;
  int tot = 0;
  if (t < nbuck)
#pragma unroll 8
    for (int c = 0; c < NCHUNK; ++c) tot += cnt[t * NCHUNK + c];
  int inc = tot;
#pragma unroll
  for (int o = 1; o < 64; o <<= 1) {
    int u = __shfl_up(inc, o, 64);
    if (lane >= o) inc += u;
  }
  if (lane == 63) ws4[w] = inc;
  __syncthreads();
  if (t == 0) {
    int run = 0;
#pragma unroll
    for (int k = 0; k < 4; ++k) { int v = ws4[k]; ws4[k + 4] = run; run += v; }
  }
  __syncthreads();
  const int base = ws4[w + 4] + inc - tot;
  if (t < nbuck) {
    bases[t] = base;
    int run = base;
    for (int c = 0; c < NCHUNK; ++c) {
      off[t * NCHUNK + c] = run;
      run += cnt[t * NCHUNK + c];
    }
  }
  if (t == 0) bases[nbuck] = E;
}

__global__ __launch_bounds__(256) void csr_bucket(const void* __restrict__ ep,
                                                  const int* __restrict__ off,
                                                  unsigned* __restrict__ tmp,
                                                  int E, int N) {
  __shared__ int cur[256];
  const int chunk = blockIdx.x;
  const int nbuck = (N + 255) >> 8;
  if ((int)threadIdx.x < nbuck) cur[threadIdx.x] = off[threadIdx.x * NCHUNK + chunk];
  __syncthreads();
  int is64 = wave_is64(ep);
  const int per = (E + NCHUNK - 1) / NCHUNK;
  const int e0 = chunk * per, e1 = min(e0 + per, E);
  for (int e = e0 + (int)threadIdx.x; e < e1; e += 256) {
    int s = edge_at(ep, is64, e);
    int d = edge_at(ep, is64, (long long)E + e);
    s = min(max(s, 0), N - 1);
    d = min(max(d, 0), N - 1);
    int pos = atomicAdd(&cur[d >> 8], 1);
    tmp[pos] = ((unsigned)d << 16) | (unsigned)s;
  }
}

__global__ __launch_bounds__(256) void csr_final(const unsigned* __restrict__ tmp,
                                                 const int* __restrict__ bases,
                                                 int* __restrict__ rp,
                                                 float* __restrict__ dis,
                                                 u16* __restrict__ col, int N, int E) {
  __shared__ int hcnt[256];
  __shared__ int curs[256];
  __shared__ int ws4[8];
  const int b = blockIdx.x;
  const int node0 = b * 256;
  const int t = threadIdx.x, lane = t & 63, w = t >> 6;
  hcnt[t] = 0;
  __syncthreads();
  const int k0 = bases[b];
  const int k1 = bases[b + 1];
  for (int k = k0 + t; k < k1; k += 256)
    atomicAdd(&hcnt[(int)(tmp[k] >> 16) - node0], 1);
  __syncthreads();
  const int v = hcnt[t];
  int inc = v;
#pragma unroll
  for (int o = 1; o < 64; o <<= 1) {
    int u = __shfl_up(inc, o, 64);
    if (lane >= o) inc += u;
  }
  if (lane == 63) ws4[w] = inc;
  __syncthreads();
  if (t == 0) {
    int run = 0;
#pragma unroll
    for (int k = 0; k < 4; ++k) { int vv = ws4[k]; ws4[k + 4] = run; run += vv; }
  }
  __syncthreads();
  const int excl = k0 + ws4[w + 4] + inc - v;
  if (node0 + t < N) {
    rp[node0 + t] = excl;
    dis[node0 + t] = rsqrtf((float)(v + 1));   // +1 = self loop
  }
  if (b == 0 && t == 0) rp[N] = E;
  curs[t] = excl;
  __syncthreads();
  for (int k = k0 + t; k < k1; k += 256) {
    unsigned e = tmp[k];
    int dl = (int)(e >> 16) - node0;
    int pos = atomicAdd(&curs[dl], 1);
    col[pos] = (u16)(e & 0xFFFFu);
  }
}

// ---------------- B-resident GEMM: C[M,Nt] = A[M,256] @ Bt[Nt,256]^T ---------
// OUT8=1: write C as fp8-e4m3 bytes; else f16.
template <int BN, int OUT8>
__global__ __launch_bounds__(256) void gemm_bres(const u16* __restrict__ A,
                                                 const u16* __restrict__ Bt,
                                                 void* __restrict__ Cv, int Nt) {
  constexpr int K = 256;
  constexpr int NJ = BN / 16;
  constexpr int CH = BN * K / 8;
  __shared__ __align__(16) u16 Bs[BN * K];

  const int tid = threadIdx.x, lane = tid & 63, w = tid >> 6;
  const int bm = blockIdx.x, bn = blockIdx.y;

#pragma unroll
  for (int i = 0; i < CH / 256; ++i) {
    int c = tid + i * 256;
    int ln = c & 63, t2 = c >> 6;
    int ks = t2 & 7, j = t2 >> 3;
    int row = j * 16 + (ln & 15);
    int kk = ks * 32 + (ln >> 4) * 8;
    async16(&Bs[(size_t)c * 8], Bt + (size_t)(bn * BN + row) * K + kk);
  }

  const int r16 = lane & 15, quad = lane >> 4;
  const int m0 = w * 32;

  const u16* Ap0 = A + (size_t)(bm * 128 + m0 + r16) * K + quad * 8;
  const u16* Ap1 = Ap0 + 16 * K;
  f16x8 aa0[8], aa1[8];
#pragma unroll
  for (int ks = 0; ks < 8; ++ks) {
    aa0[ks] = *(const f16x8*)(Ap0 + ks * 32);
    aa1[ks] = *(const f16x8*)(Ap1 + ks * 32);
  }

  f32x4 acc[2][NJ];
  const f32x4 fzero = {0.f, 0.f, 0.f, 0.f};
#pragma unroll
  for (int i = 0; i < 2; ++i)
#pragma unroll
    for (int j = 0; j < NJ; ++j) acc[i][j] = fzero;

  __syncthreads();

#pragma unroll
  for (int ks = 0; ks < 8; ++ks) {
#pragma unroll
    for (int j = 0; j < NJ; ++j) {
      f16x8 bf = *(const f16x8*)(&Bs[(size_t)((j * 8 + ks) * 64 + lane) * 8]);
      acc[0][j] = __builtin_amdgcn_mfma_f32_16x16x32_f16(aa0[ks], bf, acc[0][j], 0, 0, 0);
      acc[1][j] = __builtin_amdgcn_mfma_f32_16x16x32_f16(aa1[ks], bf, acc[1][j], 0, 0, 0);
    }
  }
#pragma unroll
  for (int i = 0; i < 2; ++i)
#pragma unroll
    for (int j = 0; j < NJ; ++j) {
      int gr = bm * 128 + m0 + i * 16 + quad * 4;   // C/D: col=lane&15, row=quad*4+r
      int gc = bn * BN + j * 16 + r16;
#pragma unroll
      for (int r = 0; r < 4; ++r) {
        if (OUT8) {
          ((unsigned char*)Cv)[(size_t)(gr + r) * Nt + gc] = ftofp8(acc[i][j][r]);
        } else {
          ((u16*)Cv)[(size_t)(gr + r) * Nt + gc] = f2h(acc[i][j][r]);
        }
      }
    }
}

// ---------------- aggregation, d=256, fp8 input rows (256B), fp32 acc --------
// half-wave = 1 edge; lane covers 8 features (8B load); 4 loads deep.
__global__ __launch_bounds__(256) void agg_d256(const unsigned char* __restrict__ h,
                                                const int* __restrict__ rp,
                                                const u16* __restrict__ col,
                                                const float* __restrict__ dis,
                                                const float* __restrict__ bias,
                                                u16* __restrict__ out, int N) {
  const int wid = threadIdx.x >> 6, lane = threadIdx.x & 63;
  const int i = blockIdx.x * 4 + wid;
  if (i >= N) return;
  const int sub = lane >> 5;
  const int l32 = lane & 31;
  const int c8 = l32 * 8;         // feature index == byte offset (1B/feature)
  const float di = dis[i];
  float a[8] = {0.f, 0.f, 0.f, 0.f, 0.f, 0.f, 0.f, 0.f};
  if (sub == 0) {                 // self term once
    uint2 sv = *(const uint2*)(h + (size_t)i * 256 + c8);
    fma8p(a, di, sv);
  }
  const int e1 = rp[i + 1];
  for (int base = rp[i]; base < e1; base += 64) {
    int me = base + lane;
    int s_l = 0; float d_l = 0.f;
    if (me < e1) { s_l = (int)col[me]; d_l = dis[s_l]; }
    const int cnt = min(64, e1 - base);
    const int cntR = (cnt + 7) & ~7;
    for (int t = 0; t < cntR; t += 8) {    // 8 edges/iter, 4 loads deep per lane
      int sA = __shfl(s_l, t + sub, 64);      float dA = __shfl(d_l, t + sub, 64);
      int sB = __shfl(s_l, t + 2 + sub, 64);  float dB = __shfl(d_l, t + 2 + sub, 64);
      int sC = __shfl(s_l, t + 4 + sub, 64);  float dC = __shfl(d_l, t + 4 + sub, 64);
      int sD = __shfl(s_l, t + 6 + sub, 64);  float dD = __shfl(d_l, t + 6 + sub, 64);
      uint2 pA = *(const uint2*)(h + (size_t)sA * 256 + c8);
      uint2 pB = *(const uint2*)(h + (size_t)sB * 256 + c8);
      uint2 pC = *(const uint2*)(h + (size_t)sC * 256 + c8);
      uint2 pD = *(const uint2*)(h + (size_t)sD * 256 + c8);
      fma8p(a, dA, pA); fma8p(a, dB, pB); fma8p(a, dC, pC); fma8p(a, dD, pD);
    }
  }
#pragma unroll
  for (int k = 0; k < 8; ++k) a[k] += __shfl_xor(a[k], 32, 64);
  if (sub == 0) {
    float4 b0 = *(const float4*)(bias + c8);
    float4 b1 = *(const float4*)(bias + c8 + 4);
    float r0 = fmaxf(di * a[0] + b0.x, 0.f), r1 = fmaxf(di * a[1] + b0.y, 0.f);
    float r2 = fmaxf(di * a[2] + b0.z, 0.f), r3 = fmaxf(di * a[3] + b0.w, 0.f);
    float r4 = fmaxf(di * a[4] + b1.x, 0.f), r5 = fmaxf(di * a[5] + b1.y, 0.f);
    float r6 = fmaxf(di * a[6] + b1.z, 0.f), r7 = fmaxf(di * a[7] + b1.w, 0.f);
    uint4 ov;
    ov.x = (unsigned)f2h(r0) | ((unsigned)f2h(r1) << 16);
    ov.y = (unsigned)f2h(r2) | ((unsigned)f2h(r3) << 16);
    ov.z = (unsigned)f2h(r4) | ((unsigned)f2h(r5) << 16);
    ov.w = (unsigned)f2h(r6) | ((unsigned)f2h(r7) << 16);
    *(uint4*)(out + (size_t)i * 256 + c8) = ov;   // f16 out for next GEMM
  }
}

// final layer: h f16 [N,64], out fp32 [N,64], fp32 acc, 2 loads deep (R9 cfg)
__global__ __launch_bounds__(256) void agg_d64(const u16* __restrict__ h,
                                               const int* __restrict__ rp,
                                               const u16* __restrict__ col,
                                               const float* __restrict__ dis,
                                               const float* __restrict__ bias,
                                               float* __restrict__ out, int N) {
  const int wid = threadIdx.x >> 6, lane = threadIdx.x & 63;
  const int i = blockIdx.x * 4 + wid;
  if (i >= N) return;
  const int grp = lane >> 3;
  const int l8 = lane & 7;
  const int c8 = l8 * 8;
  const float di = dis[i];
  float a[8];
  {
    uint4 sv = *(const uint4*)(h + (size_t)i * 64 + c8);
    const float w = (grp == 0) ? di : 0.f;
    a[0] = w * h2f((u16)sv.x); a[1] = w * h2f((u16)(sv.x >> 16));
    a[2] = w * h2f((u16)sv.y); a[3] = w * h2f((u16)(sv.y >> 16));
    a[4] = w * h2f((u16)sv.z); a[5] = w * h2f((u16)(sv.z >> 16));
    a[6] = w * h2f((u16)sv.w); a[7] = w * h2f((u16)(sv.w >> 16));
  }
  const int e1 = rp[i + 1];
  for (int base = rp[i]; base < e1; base += 64) {
    int me = base + lane;
    int s_l = 0; float d_l = 0.f;
    if (me < e1) { s_l = (int)col[me]; d_l = dis[s_l]; }
    const int cnt = min(64, e1 - base);
    const int cntR = (cnt + 15) & ~15;
    for (int t = 0; t < cntR; t += 16) {
      int sA = __shfl(s_l, t + grp, 64);       float dA = __shfl(d_l, t + grp, 64);
      int sB = __shfl(s_l, t + 8 + grp, 64);   float dB = __shfl(d_l, t + 8 + grp, 64);
      uint4 pA = *(const uint4*)(h + (size_t)sA * 64 + c8);
      uint4 pB = *(const uint4*)(h + (size_t)sB * 64 + c8);
      fma8(a, dA, pA); fma8(a, dB, pB);
    }
  }
#pragma unroll
  for (int k = 0; k < 8; ++k) a[k] += __shfl_xor(a[k], 8, 64);
#pragma unroll
  for (int k = 0; k < 8; ++k) a[k] += __shfl_xor(a[k], 16, 64);
#pragma unroll
  for (int k = 0; k < 8; ++k) a[k] += __shfl_xor(a[k], 32, 64);
  if (lane < 8) {
    float4 b0 = *(const float4*)(bias + c8);
    float4 b1 = *(const float4*)(bias + c8 + 4);
    float4 o0, o1;
    o0.x = di * a[0] + b0.x; o0.y = di * a[1] + b0.y;
    o0.z = di * a[2] + b0.z; o0.w = di * a[3] + b0.w;
    o1.x = di * a[4] + b1.x; o1.y = di * a[5] + b1.y;
    o1.z = di * a[6] + b1.z; o1.w = di * a[7] + b1.w;
    *(float4*)(out + (size_t)i * 64 + c8) = o0;
    *(float4*)(out + (size_t)i * 64 + c8 + 4) = o1;
  }
}

// ---------------- launch ----------------
extern "C" void kernel_launch(void* const* d_in, const int* in_sizes, int n_in,
                              void* d_out, int out_size, void* d_ws, size_t ws_size,
                              hipStream_t stream) {
  if (n_in < 8) return;
  const float* x = (const float*)d_in[0];
  const void* eptr = d_in[1];
  const float* W1 = (const float*)d_in[2];
  const float* b1 = (const float*)d_in[3];
  const float* W2 = (const float*)d_in[4];
  const float* b2 = (const float*)d_in[5];
  const float* W3 = (const float*)d_in[6];
  const float* b3 = (const float*)d_in[7];
  float* out = (float*)d_out;

  const int DIN = 256, DH = 256;
  const int N = in_sizes[0] / DIN;       // 50000
  const int E = in_sizes[1] / 2;         // 800000
  const int DOUT = in_sizes[6] / DH;     // 64
  const int MT = (N + 127) / 128;        // 391
  const int Mpad = MT * 128;
  const int nbuck = (N + 255) >> 8;      // 196

  auto rnd = [](size_t b) { return (b + 255) & ~(size_t)255; };
  size_t required = 0;
  required += rnd((size_t)Mpad * DH * 2);            // xpad (f16)
  required += rnd((size_t)Mpad * DH * 2);            // hbuf (fp8 for L1/2, f16 d64 for L3)
  required += rnd((size_t)E * 2);                    // col (u16)
  required += rnd((size_t)E * 4);                    // tmp (packed pairs)
  required += rnd((size_t)(N + 1) * 4);              // rp
  required += rnd((size_t)N * 4);                    // dis
  required += rnd((size_t)DIN * DH * 2);             // wt1
  required += rnd((size_t)DH * DH * 2);              // wt2
  required += rnd((size_t)DH * DOUT * 2);            // wt3
  required += rnd((size_t)256 * NCHUNK * 4) * 2;     // cnt + offs
  required += rnd((size_t)(nbuck + 1) * 4);          // bases
  if (ws_size < required || N > 65536 || nbuck > 256 || nbuck < 1) {
    zero_f32<<<(out_size + 255) / 256, 256, 0, stream>>>(out, out_size);
    return;
  }

  char* ws = (char*)d_ws;
  size_t off0 = 0;
  auto alloc = [&](size_t bytes) {
    char* p = ws + off0;
    off0 = (off0 + bytes + 255) & ~(size_t)255;
    return p;
  };
  u16* xpad = (u16*)alloc((size_t)Mpad * DH * 2);
  unsigned char* hbuf = (unsigned char*)alloc((size_t)Mpad * DH * 2);
  u16* colb = (u16*)alloc((size_t)E * 2);
  unsigned* tmpb = (unsigned*)alloc((size_t)E * 4);
  int* rp = (int*)alloc((size_t)(N + 1) * 4);
  float* dis = (float*)alloc((size_t)N * 4);
  u16* wt1 = (u16*)alloc((size_t)DIN * DH * 2);
  u16* wt2 = (u16*)alloc((size_t)DH * DH * 2);
  u16* wt3 = (u16*)alloc((size_t)DH * DOUT * 2);
  int* cnt = (int*)alloc((size_t)256 * NCHUNK * 4);
  int* offs = (int*)alloc((size_t)256 * NCHUNK * 4);
  int* bases = (int*)alloc((size_t)(nbuck + 1) * 4);

  const int n_tot4 = Mpad * DH / 4;
  const int nb_cvt = (n_tot4 + 255) / 256;
  const int nb_w1 = (DIN * DH + 255) / 256;
  const int nb_w2 = (DH * DH + 255) / 256;
  const int nb_w3 = (DH * DOUT + 255) / 256;
  prep_all<<<nb_cvt + nb_w1 + nb_w2 + nb_w3 + NCHUNK, 256, 0, stream>>>(
      (const float4*)x, (ushort4*)xpad, N * DH / 4, n_tot4,
      W1, wt1, W2, wt2, W3, wt3, eptr, cnt,
      E, N, DIN, DH, DOUT, nb_cvt, nb_w1, nb_w2, nb_w3);

  csr_base<<<1, 256, 0, stream>>>(cnt, bases, offs, nbuck, E);
  csr_bucket<<<NCHUNK, 256, 0, stream>>>(eptr, offs, tmpb, E, N);
  csr_final<<<nbuck, 256, 0, stream>>>(tmpb, bases, rp, dis, colb, N, E);

  // layer 1: gemm f16 -> fp8 h, agg fp8 -> f16
  gemm_bres<128, 1><<<dim3(MT, DH / 128), 256, 0, stream>>>(xpad, wt1, hbuf, DH);
  agg_d256<<<(N + 3) / 4, 256, 0, stream>>>(hbuf, rp, colb, dis, b1, xpad, N);
  // layer 2
  gemm_bres<128, 1><<<dim3(MT, DH / 128), 256, 0, stream>>>(xpad, wt2, hbuf, DH);
  agg_d256<<<(N + 3) / 4, 256, 0, stream>>>(hbuf, rp, colb, dis, b2, xpad, N);
  // layer 3: gemm f16 -> f16 h3, agg_d64 -> fp32 out
  gemm_bres<64, 0><<<dim3(MT, DOUT / 64), 256, 0, stream>>>(xpad, wt3, hbuf, DOUT);
  agg_d64<<<(N + 3) / 4, 256, 0, stream>>>((const u16*)hbuf, rp, colb, dis, b3, out, N);
}

// Round 14
// 296.242 us; speedup vs baseline: 1.5892x; 1.0198x over previous
//
#include <hip/hip_runtime.h>
#include <hip/hip_fp8.h>
#include <cstdint>
#include <cstddef>

typedef unsigned short u16;
typedef _Float16 f16x8 __attribute__((ext_vector_type(8)));
typedef float f32x2 __attribute__((ext_vector_type(2)));
typedef float f32x4 __attribute__((ext_vector_type(4)));

#if defined(__has_builtin)
#if __has_builtin(__builtin_amdgcn_cvt_pk_f32_fp8) && __has_builtin(__builtin_amdgcn_cvt_pk_fp8_f32)
#define FP8_BUILTIN 1
#endif
#endif

__device__ __forceinline__ float h2f(u16 u) {
  return (float)__builtin_bit_cast(_Float16, u);
}
__device__ __forceinline__ u16 f2h(float f) {
  return __builtin_bit_cast(u16, (_Float16)f);
}
__device__ __forceinline__ unsigned char ftofp8(float f) {
#ifdef FP8_BUILTIN
  return (unsigned char)(__builtin_amdgcn_cvt_pk_fp8_f32(f, f, 0, false) & 0xFF);
#else
  return __hip_fp8_e4m3(f).__x;
#endif
}

// async 16B global -> LDS (gfx950)
__device__ __forceinline__ void async16(u16* lds, const u16* g) {
  __builtin_amdgcn_global_load_lds(
      (const __attribute__((address_space(1))) unsigned int*)g,
      (__attribute__((address_space(3))) unsigned int*)lds, 16, 0, 0);
}

// fp8 row chunk (8 bytes) -> fp32 fma
__device__ __forceinline__ void fma8p(float* a, float d, uint2 p) {
#ifdef FP8_BUILTIN
  f32x2 v0 = __builtin_amdgcn_cvt_pk_f32_fp8((int)p.x, false);
  f32x2 v1 = __builtin_amdgcn_cvt_pk_f32_fp8((int)p.x, true);
  f32x2 v2 = __builtin_amdgcn_cvt_pk_f32_fp8((int)p.y, false);
  f32x2 v3 = __builtin_amdgcn_cvt_pk_f32_fp8((int)p.y, true);
  a[0] += d * v0.x; a[1] += d * v0.y; a[2] += d * v1.x; a[3] += d * v1.y;
  a[4] += d * v2.x; a[5] += d * v2.y; a[6] += d * v3.x; a[7] += d * v3.y;
#else
  const unsigned char* b = (const unsigned char*)&p;
#pragma unroll
  for (int k = 0; k < 8; ++k) {
    __hip_fp8_e4m3 v; v.__x = b[k];
    a[k] += d * (float)v;
  }
#endif
}

// fp32 row -> f16x8 fragment
__device__ __forceinline__ f16x8 cvt8(const float* p) {
  float4 a = *(const float4*)p;
  float4 b = *(const float4*)(p + 4);
  f16x8 r;
  r[0] = (_Float16)a.x; r[1] = (_Float16)a.y; r[2] = (_Float16)a.z; r[3] = (_Float16)a.w;
  r[4] = (_Float16)b.x; r[5] = (_Float16)b.y; r[6] = (_Float16)b.z; r[7] = (_Float16)b.w;
  return r;
}

// per-wave int64-vs-int32 edge dtype detection (first 1KB, L2-hot)
__device__ __forceinline__ int wave_is64(const void* ep) {
  const unsigned* p = (const unsigned*)ep;
  const int lane = threadIdx.x & 63;
  unsigned v = p[2 * lane + 1] | p[2 * (lane + 64) + 1];
  unsigned long long bal = __ballot(v != 0u);
  return (bal == 0ull) ? 1 : 0;
}

__device__ __forceinline__ int edge_at(const void* ep, int is64, long long idx) {
  if (is64) return (int)((const long long*)ep)[idx];
  return ((const int*)ep)[idx];
}

#define NCHUNK 64

// ---------------- diagnostics / fallback ----------------
__global__ void zero_f32(float* p, int n) {
  int i = blockIdx.x * 256 + threadIdx.x;
  if (i < n) p[i] = 0.f;
}

// ---------------- prep_all: 3x transpose_w + csr_hist ----------------
__global__ __launch_bounds__(256) void prep_all(
    const float* __restrict__ W1, u16* __restrict__ wt1,
    const float* __restrict__ W2, u16* __restrict__ wt2,
    const float* __restrict__ W3, u16* __restrict__ wt3,
    const void* __restrict__ ep, int* __restrict__ cnt,
    int E, int N, int DIN, int DH, int DOUT,
    int nb_w1, int nb_w2, int nb_w3) {
  int b = blockIdx.x;
  if (b < nb_w1) {                        // wt1[n*DIN+k] = W1[k*DH+n]
    int idx = b * 256 + threadIdx.x;
    if (idx < DIN * DH) {
      int n = idx / DIN, k = idx % DIN;
      wt1[idx] = f2h(W1[k * DH + n]);
    }
    return;
  }
  b -= nb_w1;
  if (b < nb_w2) {                        // wt2[n*DH+k] = W2[k*DH+n]
    int idx = b * 256 + threadIdx.x;
    if (idx < DH * DH) {
      int n = idx / DH, k = idx % DH;
      wt2[idx] = f2h(W2[k * DH + n]);
    }
    return;
  }
  b -= nb_w2;
  if (b < nb_w3) {                        // wt3[n*DH+k] = W3[k*DOUT+n]
    int idx = b * 256 + threadIdx.x;
    if (idx < DH * DOUT) {
      int n = idx / DH, k = idx % DH;
      wt3[idx] = f2h(W3[k * DOUT + n]);
    }
    return;
  }
  b -= nb_w3;
  {                                       // per-chunk bucket histogram
    __shared__ int h[256];
    h[threadIdx.x] = 0;
    __syncthreads();
    int is64 = wave_is64(ep);
    const int per = (E + NCHUNK - 1) / NCHUNK;
    const int e0 = b * per, e1 = min(e0 + per, E);
    for (int e = e0 + (int)threadIdx.x; e < e1; e += 256) {
      int d = edge_at(ep, is64, (long long)E + e);
      d = min(max(d, 0), N - 1);
      atomicAdd(&h[d >> 8], 1);
    }
    __syncthreads();
    cnt[threadIdx.x * NCHUNK + b] = h[threadIdx.x];
  }
}

// block-wide: compute exclusive bucket bases into bl[0..nbuck] (bl[nbuck]=E)
__device__ __forceinline__ void bases_in_lds(const int* __restrict__ cnt,
                                             int nbuck, int E, int* bl, int* ws4) {
  const int t = threadIdx.x, lane = t & 63, w = t >> 6;
  int tot = 0;
  if (t < nbuck)
#pragma unroll 8
    for (int c = 0; c < NCHUNK; ++c) tot += cnt[t * NCHUNK + c];
  int inc = tot;
#pragma unroll
  for (int o = 1; o < 64; o <<= 1) {
    int u = __shfl_up(inc, o, 64);
    if (lane >= o) inc += u;
  }
  if (lane == 63) ws4[w] = inc;
  __syncthreads();
  if (t == 0) {
    int run = 0;
#pragma unroll
    for (int k = 0; k < 4; ++k) { int v = ws4[k]; ws4[k + 4] = run; run += v; }
  }
  __syncthreads();
  bl[t] = ws4[w + 4] + inc - tot;
  if (t == 0) bl[nbuck] = E;
  __syncthreads();
}

// csr_bucket: recompute bases per block, scatter chunk into bucket runs
__global__ __launch_bounds__(256) void csr_bucket(const void* __restrict__ ep,
                                                  const int* __restrict__ cnt,
                                                  unsigned* __restrict__ tmp,
                                                  int E, int N, int nbuck) {
  __shared__ int bl[257];
  __shared__ int cur[256];
  __shared__ int ws4[8];
  const int chunk = blockIdx.x;
  const int t = threadIdx.x;
  bases_in_lds(cnt, nbuck, E, bl, ws4);
  if (t < nbuck) {
    int partial = 0;
    for (int c = 0; c < chunk; ++c) partial += cnt[t * NCHUNK + c];
    cur[t] = bl[t] + partial;
  }
  __syncthreads();
  int is64 = wave_is64(ep);
  const int per = (E + NCHUNK - 1) / NCHUNK;
  const int e0 = chunk * per, e1 = min(e0 + per, E);
  for (int e = e0 + t; e < e1; e += 256) {
    int s = edge_at(ep, is64, e);
    int d = edge_at(ep, is64, (long long)E + e);
    s = min(max(s, 0), N - 1);
    d = min(max(d, 0), N - 1);
    int pos = atomicAdd(&cur[d >> 8], 1);
    tmp[pos] = ((unsigned)d << 16) | (unsigned)s;
  }
}

// csr_final: recompute bases, per-bucket node histogram -> rp/dis + col scatter
__global__ __launch_bounds__(256) void csr_final(const unsigned* __restrict__ tmp,
                                                 const int* __restrict__ cnt,
                                                 int* __restrict__ rp,
                                                 float* __restrict__ dis,
                                                 u16* __restrict__ col,
                                                 int N, int E, int nbuck) {
  __shared__ int bl[257];
  __shared__ int hcnt[256];
  __shared__ int curs[256];
  __shared__ int ws4[8];
  const int b = blockIdx.x;
  const int node0 = b * 256;
  const int t = threadIdx.x, lane = t & 63, w = t >> 6;
  bases_in_lds(cnt, nbuck, E, bl, ws4);
  const int k0 = bl[b], k1 = bl[b + 1];
  hcnt[t] = 0;
  __syncthreads();
  for (int k = k0 + t; k < k1; k += 256)
    atomicAdd(&hcnt[(int)(tmp[k] >> 16) - node0], 1);
  __syncthreads();
  const int v = hcnt[t];
  int inc = v;
#pragma unroll
  for (int o = 1; o < 64; o <<= 1) {
    int u = __shfl_up(inc, o, 64);
    if (lane >= o) inc += u;
  }
  __syncthreads();                        // ws4 reuse
  if (lane == 63) ws4[w] = inc;
  __syncthreads();
  if (t == 0) {
    int run = 0;
#pragma unroll
    for (int k = 0; k < 4; ++k) { int vv = ws4[k]; ws4[k + 4] = run; run += vv; }
  }
  __syncthreads();
  const int excl = k0 + ws4[w + 4] + inc - v;
  if (node0 + t < N) {
    rp[node0 + t] = excl;
    dis[node0 + t] = rsqrtf((float)(v + 1));   // +1 = self loop
  }
  if (b == 0 && t == 0) rp[N] = E;
  curs[t] = excl;
  __syncthreads();
  for (int k = k0 + t; k < k1; k += 256) {
    unsigned e = tmp[k];
    int dl = (int)(e >> 16) - node0;
    int pos = atomicAdd(&curs[dl], 1);
    col[pos] = (u16)(e & 0xFFFFu);
  }
}

// ---------------- B-resident GEMM: C[M,Nt] = A[M,256] @ Bt[Nt,256]^T ---------
// A32=1: A is fp32 (layer 1, reads x directly, rows clamped to Nrows).
// OUT8=1: write C as fp8-e4m3 bytes; else f16.
template <int BN, int OUT8, int A32>
__global__ __launch_bounds__(256) void gemm_bres(const void* __restrict__ A,
                                                 const u16* __restrict__ Bt,
                                                 void* __restrict__ Cv, int Nt,
                                                 int Nrows) {
  constexpr int K = 256;
  constexpr int NJ = BN / 16;
  constexpr int CH = BN * K / 8;
  __shared__ __align__(16) u16 Bs[BN * K];

  const int tid = threadIdx.x, lane = tid & 63, w = tid >> 6;
  const int bm = blockIdx.x, bn = blockIdx.y;

#pragma unroll
  for (int i = 0; i < CH / 256; ++i) {
    int c = tid + i * 256;
    int ln = c & 63, t2 = c >> 6;
    int ks = t2 & 7, j = t2 >> 3;
    int row = j * 16 + (ln & 15);
    int kk = ks * 32 + (ln >> 4) * 8;
    async16(&Bs[(size_t)c * 8], Bt + (size_t)(bn * BN + row) * K + kk);
  }

  const int r16 = lane & 15, quad = lane >> 4;
  const int m0 = w * 32;

  int row0 = bm * 128 + m0 + r16;
  int row1 = row0 + 16;
  f16x8 aa0[8], aa1[8];
  if (A32) {
    row0 = min(row0, Nrows - 1);
    row1 = min(row1, Nrows - 1);
    const float* A0 = (const float*)A + (size_t)row0 * K + quad * 8;
    const float* A1 = (const float*)A + (size_t)row1 * K + quad * 8;
#pragma unroll
    for (int ks = 0; ks < 8; ++ks) {
      aa0[ks] = cvt8(A0 + ks * 32);
      aa1[ks] = cvt8(A1 + ks * 32);
    }
  } else {
    const u16* A0 = (const u16*)A + (size_t)row0 * K + quad * 8;
    const u16* A1 = (const u16*)A + (size_t)row1 * K + quad * 8;
#pragma unroll
    for (int ks = 0; ks < 8; ++ks) {
      aa0[ks] = *(const f16x8*)(A0 + ks * 32);
      aa1[ks] = *(const f16x8*)(A1 + ks * 32);
    }
  }

  f32x4 acc[2][NJ];
  const f32x4 fzero = {0.f, 0.f, 0.f, 0.f};
#pragma unroll
  for (int i = 0; i < 2; ++i)
#pragma unroll
    for (int j = 0; j < NJ; ++j) acc[i][j] = fzero;

  __syncthreads();

#pragma unroll
  for (int ks = 0; ks < 8; ++ks) {
#pragma unroll
    for (int j = 0; j < NJ; ++j) {
      f16x8 bf = *(const f16x8*)(&Bs[(size_t)((j * 8 + ks) * 64 + lane) * 8]);
      acc[0][j] = __builtin_amdgcn_mfma_f32_16x16x32_f16(aa0[ks], bf, acc[0][j], 0, 0, 0);
      acc[1][j] = __builtin_amdgcn_mfma_f32_16x16x32_f16(aa1[ks], bf, acc[1][j], 0, 0, 0);
    }
  }
#pragma unroll
  for (int i = 0; i < 2; ++i)
#pragma unroll
    for (int j = 0; j < NJ; ++j) {
      int gr = bm * 128 + m0 + i * 16 + quad * 4;   // C/D: col=lane&15, row=quad*4+r
      int gc = bn * BN + j * 16 + r16;
#pragma unroll
      for (int r = 0; r < 4; ++r) {
        if (OUT8) {
          ((unsigned char*)Cv)[(size_t)(gr + r) * Nt + gc] = ftofp8(acc[i][j][r]);
        } else {
          ((u16*)Cv)[(size_t)(gr + r) * Nt + gc] = f2h(acc[i][j][r]);
        }
      }
    }
}

// ---------------- aggregation, d=256, fp8 input rows (256B), fp32 acc --------
__global__ __launch_bounds__(256) void agg_d256(const unsigned char* __restrict__ h,
                                                const int* __restrict__ rp,
                                                const u16* __restrict__ col,
                                                const float* __restrict__ dis,
                                                const float* __restrict__ bias,
                                                u16* __restrict__ out, int N) {
  const int wid = threadIdx.x >> 6, lane = threadIdx.x & 63;
  const int i = blockIdx.x * 4 + wid;
  if (i >= N) return;
  const int sub = lane >> 5;
  const int l32 = lane & 31;
  const int c8 = l32 * 8;
  const float di = dis[i];
  float a[8] = {0.f, 0.f, 0.f, 0.f, 0.f, 0.f, 0.f, 0.f};
  if (sub == 0) {                 // self term once
    uint2 sv = *(const uint2*)(h + (size_t)i * 256 + c8);
    fma8p(a, di, sv);
  }
  const int e1 = rp[i + 1];
  for (int base = rp[i]; base < e1; base += 64) {
    int me = base + lane;
    int s_l = 0; float d_l = 0.f;
    if (me < e1) { s_l = (int)col[me]; d_l = dis[s_l]; }
    const int cnt = min(64, e1 - base);
    const int cntR = (cnt + 7) & ~7;
    for (int t = 0; t < cntR; t += 8) {
      int sA = __shfl(s_l, t + sub, 64);      float dA = __shfl(d_l, t + sub, 64);
      int sB = __shfl(s_l, t + 2 + sub, 64);  float dB = __shfl(d_l, t + 2 + sub, 64);
      int sC = __shfl(s_l, t + 4 + sub, 64);  float dC = __shfl(d_l, t + 4 + sub, 64);
      int sD = __shfl(s_l, t + 6 + sub, 64);  float dD = __shfl(d_l, t + 6 + sub, 64);
      uint2 pA = *(const uint2*)(h + (size_t)sA * 256 + c8);
      uint2 pB = *(const uint2*)(h + (size_t)sB * 256 + c8);
      uint2 pC = *(const uint2*)(h + (size_t)sC * 256 + c8);
      uint2 pD = *(const uint2*)(h + (size_t)sD * 256 + c8);
      fma8p(a, dA, pA); fma8p(a, dB, pB); fma8p(a, dC, pC); fma8p(a, dD, pD);
    }
  }
#pragma unroll
  for (int k = 0; k < 8; ++k) a[k] += __shfl_xor(a[k], 32, 64);
  if (sub == 0) {
    float4 b0 = *(const float4*)(bias + c8);
    float4 b1 = *(const float4*)(bias + c8 + 4);
    float r0 = fmaxf(di * a[0] + b0.x, 0.f), r1 = fmaxf(di * a[1] + b0.y, 0.f);
    float r2 = fmaxf(di * a[2] + b0.z, 0.f), r3 = fmaxf(di * a[3] + b0.w, 0.f);
    float r4 = fmaxf(di * a[4] + b1.x, 0.f), r5 = fmaxf(di * a[5] + b1.y, 0.f);
    float r6 = fmaxf(di * a[6] + b1.z, 0.f), r7 = fmaxf(di * a[7] + b1.w, 0.f);
    uint4 ov;
    ov.x = (unsigned)f2h(r0) | ((unsigned)f2h(r1) << 16);
    ov.y = (unsigned)f2h(r2) | ((unsigned)f2h(r3) << 16);
    ov.z = (unsigned)f2h(r4) | ((unsigned)f2h(r5) << 16);
    ov.w = (unsigned)f2h(r6) | ((unsigned)f2h(r7) << 16);
    *(uint4*)(out + (size_t)i * 256 + c8) = ov;   // f16 out for next GEMM
  }
}

// final layer: h fp8 [N,64] (64B rows), out fp32 [N,64], fp32 acc, 2 deep
__global__ __launch_bounds__(256) void agg_d64(const unsigned char* __restrict__ h,
                                               const int* __restrict__ rp,
                                               const u16* __restrict__ col,
                                               const float* __restrict__ dis,
                                               const float* __restrict__ bias,
                                               float* __restrict__ out, int N) {
  const int wid = threadIdx.x >> 6, lane = threadIdx.x & 63;
  const int i = blockIdx.x * 4 + wid;
  if (i >= N) return;
  const int grp = lane >> 3;      // edge slot 0..7
  const int l8 = lane & 7;
  const int c8 = l8 * 8;          // byte offset, 8 features/lane
  const float di = dis[i];
  float a[8] = {0.f, 0.f, 0.f, 0.f, 0.f, 0.f, 0.f, 0.f};
  if (grp == 0) {
    uint2 sv = *(const uint2*)(h + (size_t)i * 64 + c8);
    fma8p(a, di, sv);
  }
  const int e1 = rp[i + 1];
  for (int base = rp[i]; base < e1; base += 64) {
    int me = base + lane;
    int s_l = 0; float d_l = 0.f;
    if (me < e1) { s_l = (int)col[me]; d_l = dis[s_l]; }
    const int cnt = min(64, e1 - base);
    const int cntR = (cnt + 15) & ~15;
    for (int t = 0; t < cntR; t += 16) {
      int sA = __shfl(s_l, t + grp, 64);       float dA = __shfl(d_l, t + grp, 64);
      int sB = __shfl(s_l, t + 8 + grp, 64);   float dB = __shfl(d_l, t + 8 + grp, 64);
      uint2 pA = *(const uint2*)(h + (size_t)sA * 64 + c8);
      uint2 pB = *(const uint2*)(h + (size_t)sB * 64 + c8);
      fma8p(a, dA, pA); fma8p(a, dB, pB);
    }
  }
#pragma unroll
  for (int k = 0; k < 8; ++k) a[k] += __shfl_xor(a[k], 8, 64);
#pragma unroll
  for (int k = 0; k < 8; ++k) a[k] += __shfl_xor(a[k], 16, 64);
#pragma unroll
  for (int k = 0; k < 8; ++k) a[k] += __shfl_xor(a[k], 32, 64);
  if (lane < 8) {
    float4 b0 = *(const float4*)(bias + c8);
    float4 b1 = *(const float4*)(bias + c8 + 4);
    float4 o0, o1;
    o0.x = di * a[0] + b0.x; o0.y = di * a[1] + b0.y;
    o0.z = di * a[2] + b0.z; o0.w = di * a[3] + b0.w;
    o1.x = di * a[4] + b1.x; o1.y = di * a[5] + b1.y;
    o1.z = di * a[6] + b1.z; o1.w = di * a[7] + b1.w;
    *(float4*)(out + (size_t)i * 64 + c8) = o0;
    *(float4*)(out + (size_t)i * 64 + c8 + 4) = o1;
  }
}

// ---------------- launch ----------------
extern "C" void kernel_launch(void* const* d_in, const int* in_sizes, int n_in,
                              void* d_out, int out_size, void* d_ws, size_t ws_size,
                              hipStream_t stream) {
  if (n_in < 8) return;
  const float* x = (const float*)d_in[0];
  const void* eptr = d_in[1];
  const float* W1 = (const float*)d_in[2];
  const float* b1 = (const float*)d_in[3];
  const float* W2 = (const float*)d_in[4];
  const float* b2 = (const float*)d_in[5];
  const float* W3 = (const float*)d_in[6];
  const float* b3 = (const float*)d_in[7];
  float* out = (float*)d_out;

  const int DIN = 256, DH = 256;
  const int N = in_sizes[0] / DIN;       // 50000
  const int E = in_sizes[1] / 2;         // 800000
  const int DOUT = in_sizes[6] / DH;     // 64
  const int MT = (N + 127) / 128;        // 391
  const int Mpad = MT * 128;
  const int nbuck = (N + 255) >> 8;      // 196

  auto rnd = [](size_t b) { return (b + 255) & ~(size_t)255; };
  size_t required = 0;
  required += rnd((size_t)Mpad * DH * 2);            // xpad (f16 layer-2/3 input)
  required += rnd((size_t)Mpad * DH);                // hbuf (fp8)
  required += rnd((size_t)E * 2);                    // col (u16)
  required += rnd((size_t)E * 4);                    // tmp (packed pairs)
  required += rnd((size_t)(N + 1) * 4);              // rp
  required += rnd((size_t)N * 4);                    // dis
  required += rnd((size_t)DIN * DH * 2);             // wt1
  required += rnd((size_t)DH * DH * 2);              // wt2
  required += rnd((size_t)DH * DOUT * 2);            // wt3
  required += rnd((size_t)256 * NCHUNK * 4);         // cnt
  if (ws_size < required || N > 65536 || nbuck > 256 || nbuck < 1) {
    zero_f32<<<(out_size + 255) / 256, 256, 0, stream>>>(out, out_size);
    return;
  }

  char* ws = (char*)d_ws;
  size_t off0 = 0;
  auto alloc = [&](size_t bytes) {
    char* p = ws + off0;
    off0 = (off0 + bytes + 255) & ~(size_t)255;
    return p;
  };
  u16* xpad = (u16*)alloc((size_t)Mpad * DH * 2);
  unsigned char* hbuf = (unsigned char*)alloc((size_t)Mpad * DH);
  u16* colb = (u16*)alloc((size_t)E * 2);
  unsigned* tmpb = (unsigned*)alloc((size_t)E * 4);
  int* rp = (int*)alloc((size_t)(N + 1) * 4);
  float* dis = (float*)alloc((size_t)N * 4);
  u16* wt1 = (u16*)alloc((size_t)DIN * DH * 2);
  u16* wt2 = (u16*)alloc((size_t)DH * DH * 2);
  u16* wt3 = (u16*)alloc((size_t)DH * DOUT * 2);
  int* cnt = (int*)alloc((size_t)256 * NCHUNK * 4);

  const int nb_w1 = (DIN * DH + 255) / 256;
  const int nb_w2 = (DH * DH + 255) / 256;
  const int nb_w3 = (DH * DOUT + 255) / 256;
  prep_all<<<nb_w1 + nb_w2 + nb_w3 + NCHUNK, 256, 0, stream>>>(
      W1, wt1, W2, wt2, W3, wt3, eptr, cnt,
      E, N, DIN, DH, DOUT, nb_w1, nb_w2, nb_w3);

  csr_bucket<<<NCHUNK, 256, 0, stream>>>(eptr, cnt, tmpb, E, N, nbuck);
  csr_final<<<nbuck, 256, 0, stream>>>(tmpb, cnt, rp, dis, colb, N, E, nbuck);

  // layer 1: gemm fp32-A -> fp8 h, agg fp8 -> f16
  gemm_bres<128, 1, 1><<<dim3(MT, DH / 128), 256, 0, stream>>>(x, wt1, hbuf, DH, N);
  agg_d256<<<(N + 3) / 4, 256, 0, stream>>>(hbuf, rp, colb, dis, b1, xpad, N);
  // layer 2: gemm f16-A -> fp8 h, agg fp8 -> f16
  gemm_bres<128, 1, 0><<<dim3(MT, DH / 128), 256, 0, stream>>>(xpad, wt2, hbuf, DH, N);
  agg_d256<<<(N + 3) / 4, 256, 0, stream>>>(hbuf, rp, colb, dis, b2, xpad, N);
  // layer 3: gemm f16-A -> fp8 h3 (64B rows), agg_d64 -> fp32 out
  gemm_bres<64, 1, 0><<<dim3(MT, DOUT / 64), 256, 0, stream>>>(xpad, wt3, hbuf, DOUT, N);
  agg_d64<<<(N + 3) / 4, 256, 0, stream>>>(hbuf, rp, colb, dis, b3, out, N);
}